// Round 10
// baseline (908.239 us; speedup 1.0000x reference)
//
#include <hip/hip_runtime.h>
#include <hip/hip_bf16.h>

#define DEVI __device__ __forceinline__

typedef __attribute__((ext_vector_type(8))) short short8;
typedef __attribute__((ext_vector_type(4))) float f32x4;
typedef unsigned int u32;
typedef unsigned short u16;

typedef __attribute__((address_space(1))) const u32 gu32_t;
typedef __attribute__((address_space(3))) u32 lu32_t;

DEVI u16 f2bf(float f) {
  u32 u = __builtin_bit_cast(u32, f);
  u32 r = (u + 0x7fffu + ((u >> 16) & 1u)) >> 16;
  return (u16)r;
}

DEVI f32x4 mfma16(short8 a, short8 b, f32x4 c) {
  return __builtin_amdgcn_mfma_f32_16x16x32_bf16(a, b, c, 0, 0, 0);
}

DEVI void gload16(const void* g, void* l) {
  __builtin_amdgcn_global_load_lds((gu32_t*)g, (lu32_t*)l, 16, 0, 0);
}

DEVI float gelu_t(float v) {
  const float u = v * (0.7978845608f + 0.0356774081f * v * v);
  const float t = 1.0f - 2.0f / (__expf(2.0f * u) + 1.0f);
  return 0.5f * v * (1.0f + t);
}

#define CHUNK_ROWS 25088   // 512 windows * 49 tokens
#define PLANE ((size_t)CHUNK_ROWS * 64)
#define KOFF  ((size_t)8 * PLANE)          // k planes base
#define VOFF  ((size_t)16 * PLANE)         // v planes base (linear)

// ---------------- weight f32 -> bf16 ----------------
__global__ __launch_bounds__(256) void convk(const float* __restrict__ s, u16* __restrict__ d, int n4) {
  int i = blockIdx.x * 256 + threadIdx.x;
  if (i < n4) {
    const float4 v = ((const float4*)s)[i];
    ushort4 o;
    o.x = f2bf(v.x); o.y = f2bf(v.y); o.z = f2bf(v.z); o.w = f2bf(v.w);
    ((ushort4*)d)[i] = o;
  }
}

// ---------------- fused bias+mask+pad table: [4 cls][8 h][64 n][64 m] f32 ----------------
__global__ __launch_bounds__(256) void btab_build(const float* __restrict__ rpb, float* __restrict__ btab) {
  const int cls = blockIdx.x >> 3, h = blockIdx.x & 7;
  float* dst = btab + (size_t)(cls * 8 + h) * 4096;
  for (int e = threadIdx.x; e < 4096; e += 256) {
    const int n = e >> 6, m = e & 63;
    float v;
    if (m >= 49) {
      v = -1e30f;
    } else if (n >= 49) {
      v = 0.f;
    } else {
      const int r1 = n / 7, c1 = n - r1 * 7;
      const int r2 = m / 7, c2 = m - r2 * 7;
      const int rel = (r1 - r2 + 6) * 13 + (c1 - c2 + 6);
      v = rpb[rel * 8 + h];
      const int reg1 = ((cls & 1) ? (r1 < 4 ? 1 : 2) : 0) * 3 + ((cls & 2) ? (c1 < 4 ? 1 : 2) : 0);
      const int reg2 = ((cls & 1) ? (r2 < 4 ? 1 : 2) : 0) * 3 + ((cls & 2) ? (c2 < 4 ? 1 : 2) : 0);
      if (reg1 != reg2) v -= 100.f;
    }
    dst[e] = v;
  }
}

// ---------------- LN1 + shift + window gather -> XY bf16 [CHUNK_ROWS][512] ----------------
__global__ __launch_bounds__(256) void ln_gather(
    const float* __restrict__ x, const float* __restrict__ y,
    const float* __restrict__ g1, const float* __restrict__ b1,
    u16* __restrict__ XY, int rowbase)
{
  const int wv = threadIdx.x >> 6, lane = threadIdx.x & 63;
  const int rl = blockIdx.x * 4 + wv;
  const int row = rowbase + rl;
  const int w = row / 49, n = row - w * 49;
  const int b = w >> 6, win = w & 63, wh = win >> 3, ww = win & 7;
  const int r = n / 7, c = n - r * 7;
  int oh = wh * 7 + r + 3; if (oh >= 56) oh -= 56;
  int ow = ww * 7 + c + 3; if (ow >= 56) ow -= 56;
  const size_t po = ((size_t)b * 3136 + oh * 56 + ow) * 256;
  const float4 g1v = ((const float4*)g1)[lane];
  const float4 b1v = ((const float4*)b1)[lane];
  u16* orow = XY + (size_t)rl * 512;
  #pragma unroll
  for (int mod = 0; mod < 2; ++mod) {
    const float* src = (mod ? y : x) + po;
    const float4 v = ((const float4*)src)[lane];
    float s = v.x + v.y + v.z + v.w;
    #pragma unroll
    for (int off = 1; off < 64; off <<= 1) s += __shfl_xor(s, off);
    const float mean = s * (1.0f / 256.0f);
    const float d0 = v.x - mean, d1 = v.y - mean, d2 = v.z - mean, d3 = v.w - mean;
    float sq = d0 * d0 + d1 * d1 + d2 * d2 + d3 * d3;
    #pragma unroll
    for (int off = 1; off < 64; off <<= 1) sq += __shfl_xor(sq, off);
    const float rstd = rsqrtf(sq * (1.0f / 256.0f) + 1e-5f);
    ushort4 o;
    o.x = f2bf(d0 * rstd * g1v.x + b1v.x);
    o.y = f2bf(d1 * rstd * g1v.y + b1v.y);
    o.z = f2bf(d2 * rstd * g1v.z + b1v.z);
    o.w = f2bf(d3 * rstd * g1v.w + b1v.w);
    *(ushort4*)(orow + mod * 256 + lane * 4) = o;
  }
}

// ---------------- QKV GEMM (128x128, XCD-swizzled): M=25088, N=1536, K=512 ----------------
// C-tile routed through LDS (overlay of sA/sB) -> coalesced b128 stores per head.
__global__ __launch_bounds__(256) void qkv_gemm(
    const u16* __restrict__ A, const u16* __restrict__ Bw,
    const float* __restrict__ bias, u16* __restrict__ Qo)
{
  __shared__ __align__(16) u16 smem[128 * 128];   // 32 KB: sA|sB during K loop, C-tile after
  u16* sA = smem;
  u16* sB = smem + 128 * 64;
  const int nx = gridDim.x;
  const int nwg = nx * gridDim.y;
  const int orig = blockIdx.y * nx + blockIdx.x;
  const int sw = (orig & 7) * (nwg >> 3) + (orig >> 3);
  const int m0  = (sw / nx) * 128;
  const int nn0 = (sw % nx) * 128;
  const int tid = threadIdx.x;
  const int lane = tid & 63;
  const int wv = tid >> 6;
  const int wm = wv >> 1, wn = wv & 1;
  const int rq = lane & 15, kg = lane >> 4;
  f32x4 acc[4][4];
  #pragma unroll
  for (int i = 0; i < 4; ++i)
    #pragma unroll
    for (int j = 0; j < 4; ++j) acc[i][j] = f32x4{0,0,0,0};

  for (int kt = 0; kt < 8; ++kt) {
    if (kt) __syncthreads();
    #pragma unroll
    for (int i = 0; i < 4; ++i) {
      const int c = i * 256 + tid;
      gload16(A + (size_t)(m0 + (c >> 3)) * 512 + kt * 64 + (c & 7) * 8, sA + c * 8);
    }
    #pragma unroll
    for (int i = 0; i < 4; ++i) {
      const int c = i * 256 + tid;
      gload16(Bw + (size_t)(nn0 + (c >> 3)) * 512 + kt * 64 + (c & 7) * 8, sB + c * 8);
    }
    __syncthreads();
    #pragma unroll
    for (int k0 = 0; k0 < 2; ++k0) {
      short8 af[4], bf8[4];
      #pragma unroll
      for (int mt = 0; mt < 4; ++mt)
        af[mt] = *(const short8*)(sA + (wm * 64 + mt * 16 + rq) * 64 + k0 * 32 + kg * 8);
      #pragma unroll
      for (int nt = 0; nt < 4; ++nt)
        bf8[nt] = *(const short8*)(sB + (wn * 64 + nt * 16 + rq) * 64 + k0 * 32 + kg * 8);
      #pragma unroll
      for (int mt = 0; mt < 4; ++mt)
        #pragma unroll
        for (int nt = 0; nt < 4; ++nt)
          acc[mt][nt] = mfma16(af[mt], bf8[nt], acc[mt][nt]);
    }
  }
  // ---- C tile -> LDS (swizzled), then coalesced stores ----
  __syncthreads();
  const int t = nn0 >> 9;
  const int hbase = (nn0 & 511) >> 6;
  const float sc = (t == 0) ? 0.17677669529663687f : 1.0f;
  #pragma unroll
  for (int nt = 0; nt < 4; ++nt) {
    const int col = wn * 64 + nt * 16 + rq;           // local 0..127
    const float bc = bias[nn0 + col];
    const int c = col >> 3;
    #pragma unroll
    for (int mt = 0; mt < 4; ++mt)
      #pragma unroll
      for (int r = 0; r < 4; ++r) {
        const int row = wm * 64 + mt * 16 + kg * 4 + r;  // local 0..127
        smem[row * 128 + (((c & 8) | ((c ^ row) & 7)) << 3) + (col & 7)] =
            f2bf((acc[mt][nt][r] + bc) * sc);
      }
  }
  __syncthreads();
  #pragma unroll
  for (int it = 0; it < 8; ++it) {
    const int cc = it * 256 + tid;
    const int row = cc >> 4, c = cc & 15;
    const int col = c * 8;
    const int hh = col >> 6, d = col & 63;
    const short8 v = *(const short8*)(smem + row * 128 + (((c & 8) | ((c ^ row) & 7)) << 3));
    *(short8*)(Qo + (size_t)(t * 8 + hbase + hh) * PLANE + (size_t)(m0 + row) * 64 + d) = v;
  }
}

// ---------------- barrier-free attention: one wave per (window, head), table-driven softmax ----------------
__global__ __launch_bounds__(256, 3) void attn3(
    const u16* __restrict__ qkv, const float* __restrict__ btab,
    u16* __restrict__ concat, int wbase)
{
  __shared__ __align__(16) u16 sP[4][3136];    // per-wave P / out buffer (49 x 64, swizzled)
  __shared__ __align__(16) u16 sVT[4][4608];   // per-wave vT: [d][tok^((d>>3)&3)<<4], stride 72

  const int tid = threadIdx.x;
  const int wv = tid >> 6, lane = tid & 63;
  const int rq = lane & 15, kg = lane >> 4;
  const int gw = blockIdx.x * 4 + wv;
  const int wl = gw >> 3, h = gw & 7;
  const int w = wbase + wl;
  const int win = w & 63, wh = win >> 3, ww = win & 7;
  const int cls = ((wh == 7) ? 1 : 0) | ((ww == 7) ? 2 : 0);
  const float* Tb = btab + (size_t)(cls * 8 + h) * 4096;
  u16* sPw = sP[wv];
  u16* sVw = sVT[wv];

  const u16* qbase = qkv + (size_t)h * PLANE + (size_t)wl * 49 * 64;
  const u16* kbase = qkv + KOFF + (size_t)h * PLANE + (size_t)wl * 49 * 64;
  const u16* vbase = qkv + VOFF + (size_t)h * PLANE + (size_t)wl * 49 * 64;

  // ---- issue v row loads early (hidden under QK^T) ----
  short8 vreg[4][2];
  #pragma unroll
  for (int t = 0; t < 4; ++t)
    #pragma unroll
    for (int h2 = 0; h2 < 2; ++h2)
      vreg[t][h2] = *(const short8*)(vbase + (size_t)(16 * t + rq) * 64 + kg * 8 + h2 * 32);

  // ---- K fragments (all), then S with per-i Q loads ----
  short8 ak[4][2];
  #pragma unroll
  for (int j = 0; j < 4; ++j) {
    const int rr = (16 * j + rq) > 48 ? 48 : (16 * j + rq);
    ak[j][0] = *(const short8*)(kbase + rr * 64 + kg * 8);
    ak[j][1] = *(const short8*)(kbase + rr * 64 + 32 + kg * 8);
  }
  f32x4 sacc[4][4];
  #pragma unroll
  for (int i = 0; i < 4; ++i)
    #pragma unroll
    for (int j = 0; j < 4; ++j) sacc[i][j] = f32x4{0,0,0,0};
  #pragma unroll
  for (int i = 0; i < 4; ++i) {
    const int rr = (16 * i + rq) > 48 ? 48 : (16 * i + rq);
    const short8 a0 = *(const short8*)(qbase + rr * 64 + kg * 8);
    const short8 a1 = *(const short8*)(qbase + rr * 64 + 32 + kg * 8);
    #pragma unroll
    for (int j = 0; j < 4; ++j) {
      sacc[i][j] = mfma16(a0, ak[j][0], sacc[i][j]);
      sacc[i][j] = mfma16(a1, ak[j][1], sacc[i][j]);
    }
  }

  // ---- write v into LDS vT (conflict-free: row ^ (kg<<4)) ----
  #pragma unroll
  for (int t = 0; t < 4; ++t) {
    const int row = 16 * t + rq;
    #pragma unroll
    for (int h2 = 0; h2 < 2; ++h2) {
      const int c0 = kg * 8 + h2 * 32;
      #pragma unroll
      for (int j = 0; j < 8; ++j)
        sVw[(c0 + j) * 72 + (row ^ (kg << 4))] = (u16)vreg[t][h2][j];
    }
  }

  // ---- table-driven softmax; P -> sPw (swizzled) ----
  #pragma unroll
  for (int i = 0; i < 4; ++i) {
    #pragma unroll
    for (int r = 0; r < 4; ++r) {
      const int n = 16 * i + kg * 4 + r;
      const float* Trow = Tb + n * 64 + rq;
      float pv[4];
      #pragma unroll
      for (int j = 0; j < 4; ++j)
        pv[j] = sacc[i][j][r] + Trow[16 * j];
      float mx = fmaxf(fmaxf(pv[0], pv[1]), fmaxf(pv[2], pv[3]));
      #pragma unroll
      for (int off = 1; off < 16; off <<= 1) mx = fmaxf(mx, __shfl_xor(mx, off));
      float sm = 0.f;
      #pragma unroll
      for (int j = 0; j < 4; ++j) { const float e = __expf(pv[j] - mx); pv[j] = e; sm += e; }
      #pragma unroll
      for (int off = 1; off < 16; off <<= 1) sm += __shfl_xor(sm, off);
      const float inv = 1.0f / sm;
      if (n < 49) {
        #pragma unroll
        for (int j = 0; j < 4; ++j) {
          const int col = 16 * j + rq;
          sPw[n * 64 + (((col >> 3) ^ (n & 7)) << 3) + (col & 7)] = f2bf(pv[j] * inv);
        }
      }
    }
  }

  // ---- PV: A = P (LDS), B = vT (LDS b128, pad toks masked) ----
  f32x4 oacc[4][4];
  #pragma unroll
  for (int i = 0; i < 4; ++i)
    #pragma unroll
    for (int j = 0; j < 4; ++j) oacc[i][j] = f32x4{0,0,0,0};
  #pragma unroll
  for (int m0v = 0; m0v < 2; ++m0v) {
    short8 av[4];
    #pragma unroll
    for (int ct = 0; ct < 4; ++ct) {
      const int col = ct * 16 + rq;
      const int s = (col >> 3) & 3;
      short8 vvv = *(const short8*)(sVw + col * 72 + ((m0v * 32 + kg * 8) ^ (s << 4)));
      if (m0v == 1) {
        if (kg == 3) {
          #pragma unroll
          for (int e = 0; e < 8; ++e) vvv[e] = 0;
        } else if (kg == 2) {
          #pragma unroll
          for (int e = 1; e < 8; ++e) vvv[e] = 0;
        }
      }
      av[ct] = vvv;
    }
    #pragma unroll
    for (int i = 0; i < 4; ++i) {
      const int rr = (16 * i + rq) > 48 ? 48 : (16 * i + rq);
      const int ch = (m0v * 4 + kg) ^ (rr & 7);
      const short8 pa = *(const short8*)(sPw + rr * 64 + ch * 8);
      #pragma unroll
      for (int ct = 0; ct < 4; ++ct)
        oacc[i][ct] = mfma16(pa, av[ct], oacc[i][ct]);
    }
  }

  // ---- repack out_h through LDS (reuse sPw), coalesced b128 store ----
  __builtin_amdgcn_s_waitcnt(0);
  #pragma unroll
  for (int i = 0; i < 4; ++i)
    #pragma unroll
    for (int ct = 0; ct < 4; ++ct)
      #pragma unroll
      for (int r = 0; r < 4; ++r) {
        const int n = 16 * i + kg * 4 + r;
        if (n < 49) {
          const int col = ct * 16 + rq;
          sPw[n * 64 + (((col >> 3) ^ (n & 7)) << 3) + (col & 7)] = f2bf(oacc[i][ct][r]);
        }
      }
  u16* crow = concat + (size_t)(wl * 49) * 512 + h * 64;
  #pragma unroll
  for (int it = 0; it < 7; ++it) {
    const int c = it * 64 + lane;
    if (c < 392) {
      const int m = c >> 3, s = c & 7;
      const short8 vvv = *(const short8*)(sPw + m * 64 + ((s ^ (m & 7)) << 3));
      *(short8*)(crow + (size_t)m * 512 + s * 8) = vvv;
    }
  }
}

// ---------------- proj GEMM + LN2 fused: BM=128, BN=256 (full row); grid 196 ----------------
__global__ __launch_bounds__(256, 2) void projln(
    const u16* __restrict__ A, const u16* __restrict__ Bw,
    const float* __restrict__ bias, const float* __restrict__ x,
    const float* __restrict__ g2, const float* __restrict__ b2,
    float* __restrict__ out, u16* __restrict__ xn2, int rowbase)
{
  __shared__ __align__(16) u16 sA[128 * 64];
  __shared__ __align__(16) u16 sB[256 * 64];
  const int m0 = blockIdx.x * 128;
  const int tid = threadIdx.x;
  const int lane = tid & 63;
  const int wv = tid >> 6;
  const int rq = lane & 15, kg = lane >> 4;
  f32x4 acc[2][16];
  #pragma unroll
  for (int i = 0; i < 2; ++i)
    #pragma unroll
    for (int j = 0; j < 16; ++j) acc[i][j] = f32x4{0,0,0,0};

  for (int kt = 0; kt < 8; ++kt) {
    if (kt) __syncthreads();
    #pragma unroll
    for (int i = 0; i < 4; ++i) {
      const int c = i * 256 + tid;
      gload16(A + (size_t)(m0 + (c >> 3)) * 512 + kt * 64 + (c & 7) * 8, sA + c * 8);
    }
    #pragma unroll
    for (int i = 0; i < 8; ++i) {
      const int c = i * 256 + tid;
      gload16(Bw + (size_t)(c >> 3) * 512 + kt * 64 + (c & 7) * 8, sB + c * 8);
    }
    __syncthreads();
    #pragma unroll
    for (int k0 = 0; k0 < 2; ++k0) {
      short8 af[2];
      #pragma unroll
      for (int mt = 0; mt < 2; ++mt)
        af[mt] = *(const short8*)(sA + (wv * 32 + mt * 16 + rq) * 64 + k0 * 32 + kg * 8);
      #pragma unroll
      for (int nt = 0; nt < 16; ++nt) {
        const short8 bf8 = *(const short8*)(sB + (nt * 16 + rq) * 64 + k0 * 32 + kg * 8);
        #pragma unroll
        for (int mt = 0; mt < 2; ++mt)
          acc[mt][nt] = mfma16(af[mt], bf8, acc[mt][nt]);
      }
    }
  }

  float br[16], g2r[16], b2r[16];
  #pragma unroll
  for (int nt = 0; nt < 16; ++nt) {
    const int col = nt * 16 + rq;
    br[nt] = bias[col]; g2r[nt] = g2[col]; b2r[nt] = b2[col];
  }
  #pragma unroll
  for (int mt = 0; mt < 2; ++mt) {
    #pragma unroll
    for (int r = 0; r < 4; ++r) {
      const int row = m0 + wv * 32 + mt * 16 + kg * 4 + r;
      const u32 g = (u32)(rowbase + row);
      const u32 w = g / 49u; const u32 n = g - w * 49u;
      const int b = w >> 6, win = w & 63, wh = win >> 3, ww = win & 7;
      const u32 rr = n / 7u; const u32 cc = n - rr * 7u;
      int oh = wh * 7 + (int)rr + 3; if (oh >= 56) oh -= 56;
      int ow = ww * 7 + (int)cc + 3; if (ow >= 56) ow -= 56;
      const size_t po = ((size_t)b * 3136 + oh * 56 + ow) * 256;
      float vals[16];
      float s = 0.f;
      #pragma unroll
      for (int nt = 0; nt < 16; ++nt) {
        const float v = acc[mt][nt][r] + br[nt] + x[po + nt * 16 + rq];
        vals[nt] = v; s += v;
      }
      #pragma unroll
      for (int off = 1; off < 16; off <<= 1) s += __shfl_xor(s, off);
      const float mean = s * (1.0f / 256.0f);
      float sq = 0.f;
      #pragma unroll
      for (int nt = 0; nt < 16; ++nt) { const float d_ = vals[nt] - mean; sq += d_ * d_; }
      #pragma unroll
      for (int off = 1; off < 16; off <<= 1) sq += __shfl_xor(sq, off);
      const float rstd = rsqrtf(sq * (1.0f / 256.0f) + 1e-5f);
      #pragma unroll
      for (int nt = 0; nt < 16; ++nt) {
        const int col = nt * 16 + rq;
        out[po + col] = vals[nt];
        xn2[po + col] = f2bf((vals[nt] - mean) * rstd * g2r[nt] + b2r[nt]);
      }
    }
  }
}

// ---------------- fused MLP v3: software-pipelined weight loads, h stays in LDS ----------------
// 8 phases of 128 h-cols; fc1 ring-4 prefetch; fc2 weights prefetched under GELU.
__global__ __launch_bounds__(256, 3) void fused_mlp(
    const u16* __restrict__ xn2, const u16* __restrict__ w1,
    const float* __restrict__ bf1, const u16* __restrict__ w2,
    const float* __restrict__ bf2v, float* __restrict__ out)
{
  __shared__ __align__(16) u16 sX[64 * 256];   // 32 KB, chunk-swizzled
  __shared__ __align__(16) u16 sH[64 * 128];   // 16 KB, chunk-swizzled

  const int m0 = blockIdx.x * 64;
  const int tid = threadIdx.x;
  const int wv = tid >> 6, lane = tid & 63;
  const int rq = lane & 15, kg = lane >> 4;

  // stage xn2 panel (pre-swizzled global source, linear LDS dest)
  #pragma unroll
  for (int i = 0; i < 8; ++i) {
    const int c = i * 256 + tid;
    const int row = c >> 5, ch = c & 31;
    const int sch = (ch & 24) | ((ch ^ row) & 7);
    gload16(xn2 + (size_t)(m0 + row) * 256 + sch * 8, sX + c * 8);
  }

  f32x4 acc2[4][4];
  #pragma unroll
  for (int i = 0; i < 4; ++i)
    #pragma unroll
    for (int j = 0; j < 4; ++j) acc2[i][j] = f32x4{0,0,0,0};

  __syncthreads();

  for (int t = 0; t < 8; ++t) {
    // ---- fc1: ring-4 software pipeline over ks = 0..8 ----
    short8 w1f[4][2];
    #pragma unroll
    for (int p = 0; p < 3; ++p)
      #pragma unroll
      for (int nt = 0; nt < 2; ++nt)
        w1f[p][nt] = *(const short8*)(w1 + (size_t)(t * 128 + wv * 32 + nt * 16 + rq) * 256 + p * 32 + kg * 8);
    f32x4 a1[4][2];
    #pragma unroll
    for (int i = 0; i < 4; ++i)
      #pragma unroll
      for (int j = 0; j < 2; ++j) a1[i][j] = f32x4{0,0,0,0};
    #pragma unroll
    for (int ks = 0; ks < 8; ++ks) {
      if (ks < 5) {
        #pragma unroll
        for (int nt = 0; nt < 2; ++nt)
          w1f[(ks + 3) & 3][nt] = *(const short8*)(w1 + (size_t)(t * 128 + wv * 32 + nt * 16 + rq) * 256 + (ks + 3) * 32 + kg * 8);
      }
      #pragma unroll
      for (int mt = 0; mt < 4; ++mt) {
        const int R = mt * 16 + rq;
        const int wk = ks * 4 + kg;
        const short8 af = *(const short8*)(sX + R * 256 + ((wk & 24) | ((wk ^ R) & 7)) * 8);
        #pragma unroll
        for (int nt = 0; nt < 2; ++nt)
          a1[mt][nt] = mfma16(af, w1f[ks & 3][nt], a1[mt][nt]);
      }
    }
    __syncthreads();   // prior phase's fc2 reads of sH complete
    // ---- prefetch fc2 first half (k-steps 0,1) -- latency hidden under GELU ----
    short8 w2f[2][4];
    #pragma unroll
    for (int p = 0; p < 2; ++p)
      #pragma unroll
      for (int nt = 0; nt < 4; ++nt)
        w2f[p][nt] = *(const short8*)(w2 + (size_t)(wv * 64 + nt * 16 + rq) * 1024 + t * 128 + p * 32 + kg * 8);
    // ---- bias + GELU, write h tile (swizzled) ----
    #pragma unroll
    for (int nt = 0; nt < 2; ++nt) {
      const int col = wv * 32 + nt * 16 + rq;
      const float bb = bf1[t * 128 + col];
      const int ch = col >> 3;
      #pragma unroll
      for (int mt = 0; mt < 4; ++mt)
        #pragma unroll
        for (int r = 0; r < 4; ++r) {
          const int row = mt * 16 + kg * 4 + r;
          sH[row * 128 + ((ch & 8) | ((ch ^ row) & 7)) * 8 + (col & 7)] =
              f2bf(gelu_t(a1[mt][nt][r] + bb));
        }
    }
    __syncthreads();   // h tile visible
    // ---- prefetch fc2 second half (k-steps 2,3) ----
    short8 w2g[2][4];
    #pragma unroll
    for (int p = 0; p < 2; ++p)
      #pragma unroll
      for (int nt = 0; nt < 4; ++nt)
        w2g[p][nt] = *(const short8*)(w2 + (size_t)(wv * 64 + nt * 16 + rq) * 1024 + t * 128 + (2 + p) * 32 + kg * 8);
    // ---- fc2: consume preloaded fragments (stall-free) ----
    #pragma unroll
    for (int ks = 0; ks < 2; ++ks) {
      #pragma unroll
      for (int mt = 0; mt < 4; ++mt) {
        const int R = mt * 16 + rq;
        const int wk = ks * 4 + kg;
        const short8 af = *(const short8*)(sH + R * 128 + ((wk & 8) | ((wk ^ R) & 7)) * 8);
        #pragma unroll
        for (int nt = 0; nt < 4; ++nt)
          acc2[mt][nt] = mfma16(af, w2f[ks][nt], acc2[mt][nt]);
      }
    }
    #pragma unroll
    for (int ks = 0; ks < 2; ++ks) {
      #pragma unroll
      for (int mt = 0; mt < 4; ++mt) {
        const int R = mt * 16 + rq;
        const int wk = (2 + ks) * 4 + kg;
        const short8 af = *(const short8*)(sH + R * 128 + ((wk & 8) | ((wk ^ R) & 7)) * 8);
        #pragma unroll
        for (int nt = 0; nt < 4; ++nt)
          acc2[mt][nt] = mfma16(af, w2g[ks][nt], acc2[mt][nt]);
      }
    }
  }

  // ---- epilogue: + b_fc2 + residual RMW ----
  #pragma unroll
  for (int nt = 0; nt < 4; ++nt) {
    const int col = wv * 64 + nt * 16 + rq;
    const float bb = bf2v[col];
    #pragma unroll
    for (int mt = 0; mt < 4; ++mt)
      #pragma unroll
      for (int r = 0; r < 4; ++r) {
        float* p = out + (size_t)(m0 + mt * 16 + kg * 4 + r) * 256 + col;
        *p = acc2[mt][nt][r] + bb + *p;
      }
  }
}

extern "C" void kernel_launch(void* const* d_in, const int* in_sizes, int n_in,
                              void* d_out, int out_size, void* d_ws, size_t ws_size,
                              hipStream_t stream) {
  const float* x      = (const float*)d_in[0];
  const float* y      = (const float*)d_in[1];
  const float* g1     = (const float*)d_in[2];
  const float* b1     = (const float*)d_in[3];
  const float* rpb    = (const float*)d_in[4];
  const float* w_qkv  = (const float*)d_in[5];
  const float* b_qkv  = (const float*)d_in[6];
  const float* w_proj = (const float*)d_in[7];
  const float* b_proj = (const float*)d_in[8];
  const float* g2     = (const float*)d_in[9];
  const float* b2     = (const float*)d_in[10];
  const float* w_fc1  = (const float*)d_in[11];
  const float* b_fc1  = (const float*)d_in[12];
  const float* w_fc2  = (const float*)d_in[13];
  const float* b_fc2  = (const float*)d_in[14];
  float* out = (float*)d_out;

  u16* wsp = (u16*)d_ws;
  u16* wqkv_bf  = wsp;                       //  786432
  u16* wproj_bf = wsp + 786432;              //  131072
  u16* wfc1_bf  = wsp + 917504;              //  262144
  u16* wfc2_bf  = wsp + 1179648;             //  262144
  float* btab   = (float*)(wsp + 1441792);   //  131072 f32
  u16* xn2      = wsp + 1703936;             //  25690112
  u16* XYc      = wsp + 27394048;            //  12845056 (25088 x 512)
  u16* qkvc     = wsp + 40239104;            //  24 planes x 25088 x 64

  convk<<<768, 256, 0, stream>>>(w_qkv,  wqkv_bf,  196608);
  convk<<<128, 256, 0, stream>>>(w_proj, wproj_bf, 32768);
  convk<<<256, 256, 0, stream>>>(w_fc1,  wfc1_bf,  65536);
  convk<<<256, 256, 0, stream>>>(w_fc2,  wfc2_bf,  65536);
  btab_build<<<32, 256, 0, stream>>>(rpb, btab);

  for (int c = 0; c < 4; ++c) {
    ln_gather<<<6272, 256, 0, stream>>>(x, y, g1, b1, XYc, c * CHUNK_ROWS);
    qkv_gemm<<<dim3(12, 196), 256, 0, stream>>>(XYc, wqkv_bf, b_qkv, qkvc);
    attn3<<<1024, 256, 0, stream>>>(qkvc, btab, XYc, c * 512);
    projln<<<196, 256, 0, stream>>>(XYc, wproj_bf, b_proj, x, g2, b2, out, xn2, c * CHUNK_ROWS);
  }

  fused_mlp<<<1568, 256, 0, stream>>>(xn2, wfc1_bf, b_fc1, wfc2_bf, b_fc2, out);
}

// Round 11
// 896.280 us; speedup vs baseline: 1.0133x; 1.0133x over previous
//
#include <hip/hip_runtime.h>
#include <hip/hip_bf16.h>

#define DEVI __device__ __forceinline__

typedef __attribute__((ext_vector_type(8))) short short8;
typedef __attribute__((ext_vector_type(4))) float f32x4;
typedef unsigned int u32;
typedef unsigned short u16;

typedef __attribute__((address_space(1))) const u32 gu32_t;
typedef __attribute__((address_space(3))) u32 lu32_t;

DEVI u16 f2bf(float f) {
  u32 u = __builtin_bit_cast(u32, f);
  u32 r = (u + 0x7fffu + ((u >> 16) & 1u)) >> 16;
  return (u16)r;
}

DEVI f32x4 mfma16(short8 a, short8 b, f32x4 c) {
  return __builtin_amdgcn_mfma_f32_16x16x32_bf16(a, b, c, 0, 0, 0);
}

DEVI void gload16(const void* g, void* l) {
  __builtin_amdgcn_global_load_lds((gu32_t*)g, (lu32_t*)l, 16, 0, 0);
}

// unsinkable global load: volatile asm keeps issue order; pair with
// s_waitcnt vmcnt(0) + sched_barrier(0) before first use (rule #18).
DEVI short8 gload_asm(const u16* p) {
  short8 r;
  asm volatile("global_load_dwordx4 %0, %1, off" : "=v"(r) : "v"(p));
  return r;
}

DEVI float gelu_t(float v) {
  const float u = v * (0.7978845608f + 0.0356774081f * v * v);
  const float t = 1.0f - 2.0f / (__expf(2.0f * u) + 1.0f);
  return 0.5f * v * (1.0f + t);
}

#define CHUNK_ROWS 25088   // 512 windows * 49 tokens
#define PLANE ((size_t)CHUNK_ROWS * 64)
#define KOFF  ((size_t)8 * PLANE)          // k planes base
#define VOFF  ((size_t)16 * PLANE)         // v planes base (linear)

// ---------------- weight f32 -> bf16 ----------------
__global__ __launch_bounds__(256) void convk(const float* __restrict__ s, u16* __restrict__ d, int n4) {
  int i = blockIdx.x * 256 + threadIdx.x;
  if (i < n4) {
    const float4 v = ((const float4*)s)[i];
    ushort4 o;
    o.x = f2bf(v.x); o.y = f2bf(v.y); o.z = f2bf(v.z); o.w = f2bf(v.w);
    ((ushort4*)d)[i] = o;
  }
}

// ---------------- fused bias+mask+pad table: [4 cls][8 h][64 n][64 m] f32 ----------------
__global__ __launch_bounds__(256) void btab_build(const float* __restrict__ rpb, float* __restrict__ btab) {
  const int cls = blockIdx.x >> 3, h = blockIdx.x & 7;
  float* dst = btab + (size_t)(cls * 8 + h) * 4096;
  for (int e = threadIdx.x; e < 4096; e += 256) {
    const int n = e >> 6, m = e & 63;
    float v;
    if (m >= 49) {
      v = -1e30f;
    } else if (n >= 49) {
      v = 0.f;
    } else {
      const int r1 = n / 7, c1 = n - r1 * 7;
      const int r2 = m / 7, c2 = m - r2 * 7;
      const int rel = (r1 - r2 + 6) * 13 + (c1 - c2 + 6);
      v = rpb[rel * 8 + h];
      const int reg1 = ((cls & 1) ? (r1 < 4 ? 1 : 2) : 0) * 3 + ((cls & 2) ? (c1 < 4 ? 1 : 2) : 0);
      const int reg2 = ((cls & 1) ? (r2 < 4 ? 1 : 2) : 0) * 3 + ((cls & 2) ? (c2 < 4 ? 1 : 2) : 0);
      if (reg1 != reg2) v -= 100.f;
    }
    dst[e] = v;
  }
}

// ---------------- LN1 + shift + window gather -> XY bf16 [CHUNK_ROWS][512] ----------------
__global__ __launch_bounds__(256) void ln_gather(
    const float* __restrict__ x, const float* __restrict__ y,
    const float* __restrict__ g1, const float* __restrict__ b1,
    u16* __restrict__ XY, int rowbase)
{
  const int wv = threadIdx.x >> 6, lane = threadIdx.x & 63;
  const int rl = blockIdx.x * 4 + wv;
  const int row = rowbase + rl;
  const int w = row / 49, n = row - w * 49;
  const int b = w >> 6, win = w & 63, wh = win >> 3, ww = win & 7;
  const int r = n / 7, c = n - r * 7;
  int oh = wh * 7 + r + 3; if (oh >= 56) oh -= 56;
  int ow = ww * 7 + c + 3; if (ow >= 56) ow -= 56;
  const size_t po = ((size_t)b * 3136 + oh * 56 + ow) * 256;
  const float4 g1v = ((const float4*)g1)[lane];
  const float4 b1v = ((const float4*)b1)[lane];
  u16* orow = XY + (size_t)rl * 512;
  #pragma unroll
  for (int mod = 0; mod < 2; ++mod) {
    const float* src = (mod ? y : x) + po;
    const float4 v = ((const float4*)src)[lane];
    float s = v.x + v.y + v.z + v.w;
    #pragma unroll
    for (int off = 1; off < 64; off <<= 1) s += __shfl_xor(s, off);
    const float mean = s * (1.0f / 256.0f);
    const float d0 = v.x - mean, d1 = v.y - mean, d2 = v.z - mean, d3 = v.w - mean;
    float sq = d0 * d0 + d1 * d1 + d2 * d2 + d3 * d3;
    #pragma unroll
    for (int off = 1; off < 64; off <<= 1) sq += __shfl_xor(sq, off);
    const float rstd = rsqrtf(sq * (1.0f / 256.0f) + 1e-5f);
    ushort4 o;
    o.x = f2bf(d0 * rstd * g1v.x + b1v.x);
    o.y = f2bf(d1 * rstd * g1v.y + b1v.y);
    o.z = f2bf(d2 * rstd * g1v.z + b1v.z);
    o.w = f2bf(d3 * rstd * g1v.w + b1v.w);
    *(ushort4*)(orow + mod * 256 + lane * 4) = o;
  }
}

// ---------------- QKV GEMM (128x128, XCD-swizzled): M=25088, N=1536, K=512 ----------------
// C-tile routed through LDS (overlay of sA/sB) -> coalesced b128 stores per head.
__global__ __launch_bounds__(256) void qkv_gemm(
    const u16* __restrict__ A, const u16* __restrict__ Bw,
    const float* __restrict__ bias, u16* __restrict__ Qo)
{
  __shared__ __align__(16) u16 smem[128 * 128];   // 32 KB: sA|sB during K loop, C-tile after
  u16* sA = smem;
  u16* sB = smem + 128 * 64;
  const int nx = gridDim.x;
  const int nwg = nx * gridDim.y;
  const int orig = blockIdx.y * nx + blockIdx.x;
  const int sw = (orig & 7) * (nwg >> 3) + (orig >> 3);
  const int m0  = (sw / nx) * 128;
  const int nn0 = (sw % nx) * 128;
  const int tid = threadIdx.x;
  const int lane = tid & 63;
  const int wv = tid >> 6;
  const int wm = wv >> 1, wn = wv & 1;
  const int rq = lane & 15, kg = lane >> 4;
  f32x4 acc[4][4];
  #pragma unroll
  for (int i = 0; i < 4; ++i)
    #pragma unroll
    for (int j = 0; j < 4; ++j) acc[i][j] = f32x4{0,0,0,0};

  for (int kt = 0; kt < 8; ++kt) {
    if (kt) __syncthreads();
    #pragma unroll
    for (int i = 0; i < 4; ++i) {
      const int c = i * 256 + tid;
      gload16(A + (size_t)(m0 + (c >> 3)) * 512 + kt * 64 + (c & 7) * 8, sA + c * 8);
    }
    #pragma unroll
    for (int i = 0; i < 4; ++i) {
      const int c = i * 256 + tid;
      gload16(Bw + (size_t)(nn0 + (c >> 3)) * 512 + kt * 64 + (c & 7) * 8, sB + c * 8);
    }
    __syncthreads();
    #pragma unroll
    for (int k0 = 0; k0 < 2; ++k0) {
      short8 af[4], bf8[4];
      #pragma unroll
      for (int mt = 0; mt < 4; ++mt)
        af[mt] = *(const short8*)(sA + (wm * 64 + mt * 16 + rq) * 64 + k0 * 32 + kg * 8);
      #pragma unroll
      for (int nt = 0; nt < 4; ++nt)
        bf8[nt] = *(const short8*)(sB + (wn * 64 + nt * 16 + rq) * 64 + k0 * 32 + kg * 8);
      #pragma unroll
      for (int mt = 0; mt < 4; ++mt)
        #pragma unroll
        for (int nt = 0; nt < 4; ++nt)
          acc[mt][nt] = mfma16(af[mt], bf8[nt], acc[mt][nt]);
    }
  }
  // ---- C tile -> LDS (swizzled), then coalesced stores ----
  __syncthreads();
  const int t = nn0 >> 9;
  const int hbase = (nn0 & 511) >> 6;
  const float sc = (t == 0) ? 0.17677669529663687f : 1.0f;
  #pragma unroll
  for (int nt = 0; nt < 4; ++nt) {
    const int col = wn * 64 + nt * 16 + rq;           // local 0..127
    const float bc = bias[nn0 + col];
    const int c = col >> 3;
    #pragma unroll
    for (int mt = 0; mt < 4; ++mt)
      #pragma unroll
      for (int r = 0; r < 4; ++r) {
        const int row = wm * 64 + mt * 16 + kg * 4 + r;  // local 0..127
        smem[row * 128 + (((c & 8) | ((c ^ row) & 7)) << 3) + (col & 7)] =
            f2bf((acc[mt][nt][r] + bc) * sc);
      }
  }
  __syncthreads();
  #pragma unroll
  for (int it = 0; it < 8; ++it) {
    const int cc = it * 256 + tid;
    const int row = cc >> 4, c = cc & 15;
    const int col = c * 8;
    const int hh = col >> 6, d = col & 63;
    const short8 v = *(const short8*)(smem + row * 128 + (((c & 8) | ((c ^ row) & 7)) << 3));
    *(short8*)(Qo + (size_t)(t * 8 + hbase + hh) * PLANE + (size_t)(m0 + row) * 64 + d) = v;
  }
}

// ---------------- barrier-free attention: one wave per (window, head), table-driven softmax ----------------
__global__ __launch_bounds__(256, 3) void attn3(
    const u16* __restrict__ qkv, const float* __restrict__ btab,
    u16* __restrict__ concat, int wbase)
{
  __shared__ __align__(16) u16 sP[4][3136];    // per-wave P / out buffer (49 x 64, swizzled)
  __shared__ __align__(16) u16 sVT[4][4608];   // per-wave vT: [d][tok^((d>>3)&3)<<4], stride 72

  const int tid = threadIdx.x;
  const int wv = tid >> 6, lane = tid & 63;
  const int rq = lane & 15, kg = lane >> 4;
  const int gw = blockIdx.x * 4 + wv;
  const int wl = gw >> 3, h = gw & 7;
  const int w = wbase + wl;
  const int win = w & 63, wh = win >> 3, ww = win & 7;
  const int cls = ((wh == 7) ? 1 : 0) | ((ww == 7) ? 2 : 0);
  const float* Tb = btab + (size_t)(cls * 8 + h) * 4096;
  u16* sPw = sP[wv];
  u16* sVw = sVT[wv];

  const u16* qbase = qkv + (size_t)h * PLANE + (size_t)wl * 49 * 64;
  const u16* kbase = qkv + KOFF + (size_t)h * PLANE + (size_t)wl * 49 * 64;
  const u16* vbase = qkv + VOFF + (size_t)h * PLANE + (size_t)wl * 49 * 64;

  // ---- issue v row loads early (hidden under QK^T) ----
  short8 vreg[4][2];
  #pragma unroll
  for (int t = 0; t < 4; ++t)
    #pragma unroll
    for (int h2 = 0; h2 < 2; ++h2)
      vreg[t][h2] = *(const short8*)(vbase + (size_t)(16 * t + rq) * 64 + kg * 8 + h2 * 32);

  // ---- K fragments (all), then S with per-i Q loads ----
  short8 ak[4][2];
  #pragma unroll
  for (int j = 0; j < 4; ++j) {
    const int rr = (16 * j + rq) > 48 ? 48 : (16 * j + rq);
    ak[j][0] = *(const short8*)(kbase + rr * 64 + kg * 8);
    ak[j][1] = *(const short8*)(kbase + rr * 64 + 32 + kg * 8);
  }
  f32x4 sacc[4][4];
  #pragma unroll
  for (int i = 0; i < 4; ++i)
    #pragma unroll
    for (int j = 0; j < 4; ++j) sacc[i][j] = f32x4{0,0,0,0};
  #pragma unroll
  for (int i = 0; i < 4; ++i) {
    const int rr = (16 * i + rq) > 48 ? 48 : (16 * i + rq);
    const short8 a0 = *(const short8*)(qbase + rr * 64 + kg * 8);
    const short8 a1 = *(const short8*)(qbase + rr * 64 + 32 + kg * 8);
    #pragma unroll
    for (int j = 0; j < 4; ++j) {
      sacc[i][j] = mfma16(a0, ak[j][0], sacc[i][j]);
      sacc[i][j] = mfma16(a1, ak[j][1], sacc[i][j]);
    }
  }

  // ---- write v into LDS vT (conflict-free: row ^ (kg<<4)) ----
  #pragma unroll
  for (int t = 0; t < 4; ++t) {
    const int row = 16 * t + rq;
    #pragma unroll
    for (int h2 = 0; h2 < 2; ++h2) {
      const int c0 = kg * 8 + h2 * 32;
      #pragma unroll
      for (int j = 0; j < 8; ++j)
        sVw[(c0 + j) * 72 + (row ^ (kg << 4))] = (u16)vreg[t][h2][j];
    }
  }

  // ---- table-driven softmax; P -> sPw (swizzled) ----
  #pragma unroll
  for (int i = 0; i < 4; ++i) {
    #pragma unroll
    for (int r = 0; r < 4; ++r) {
      const int n = 16 * i + kg * 4 + r;
      const float* Trow = Tb + n * 64 + rq;
      float pv[4];
      #pragma unroll
      for (int j = 0; j < 4; ++j)
        pv[j] = sacc[i][j][r] + Trow[16 * j];
      float mx = fmaxf(fmaxf(pv[0], pv[1]), fmaxf(pv[2], pv[3]));
      #pragma unroll
      for (int off = 1; off < 16; off <<= 1) mx = fmaxf(mx, __shfl_xor(mx, off));
      float sm = 0.f;
      #pragma unroll
      for (int j = 0; j < 4; ++j) { const float e = __expf(pv[j] - mx); pv[j] = e; sm += e; }
      #pragma unroll
      for (int off = 1; off < 16; off <<= 1) sm += __shfl_xor(sm, off);
      const float inv = 1.0f / sm;
      if (n < 49) {
        #pragma unroll
        for (int j = 0; j < 4; ++j) {
          const int col = 16 * j + rq;
          sPw[n * 64 + (((col >> 3) ^ (n & 7)) << 3) + (col & 7)] = f2bf(pv[j] * inv);
        }
      }
    }
  }

  // ---- PV: A = P (LDS), B = vT (LDS b128, pad toks masked) ----
  f32x4 oacc[4][4];
  #pragma unroll
  for (int i = 0; i < 4; ++i)
    #pragma unroll
    for (int j = 0; j < 4; ++j) oacc[i][j] = f32x4{0,0,0,0};
  #pragma unroll
  for (int m0v = 0; m0v < 2; ++m0v) {
    short8 av[4];
    #pragma unroll
    for (int ct = 0; ct < 4; ++ct) {
      const int col = ct * 16 + rq;
      const int s = (col >> 3) & 3;
      short8 vvv = *(const short8*)(sVw + col * 72 + ((m0v * 32 + kg * 8) ^ (s << 4)));
      if (m0v == 1) {
        if (kg == 3) {
          #pragma unroll
          for (int e = 0; e < 8; ++e) vvv[e] = 0;
        } else if (kg == 2) {
          #pragma unroll
          for (int e = 1; e < 8; ++e) vvv[e] = 0;
        }
      }
      av[ct] = vvv;
    }
    #pragma unroll
    for (int i = 0; i < 4; ++i) {
      const int rr = (16 * i + rq) > 48 ? 48 : (16 * i + rq);
      const int ch = (m0v * 4 + kg) ^ (rr & 7);
      const short8 pa = *(const short8*)(sPw + rr * 64 + ch * 8);
      #pragma unroll
      for (int ct = 0; ct < 4; ++ct)
        oacc[i][ct] = mfma16(pa, av[ct], oacc[i][ct]);
    }
  }

  // ---- repack out_h through LDS (reuse sPw), coalesced b128 store ----
  __builtin_amdgcn_s_waitcnt(0);
  #pragma unroll
  for (int i = 0; i < 4; ++i)
    #pragma unroll
    for (int ct = 0; ct < 4; ++ct)
      #pragma unroll
      for (int r = 0; r < 4; ++r) {
        const int n = 16 * i + kg * 4 + r;
        if (n < 49) {
          const int col = ct * 16 + rq;
          sPw[n * 64 + (((col >> 3) ^ (n & 7)) << 3) + (col & 7)] = f2bf(oacc[i][ct][r]);
        }
      }
  u16* crow = concat + (size_t)(wl * 49) * 512 + h * 64;
  #pragma unroll
  for (int it = 0; it < 7; ++it) {
    const int c = it * 64 + lane;
    if (c < 392) {
      const int m = c >> 3, s = c & 7;
      const short8 vvv = *(const short8*)(sPw + m * 64 + ((s ^ (m & 7)) << 3));
      *(short8*)(crow + (size_t)m * 512 + s * 8) = vvv;
    }
  }
}

// ---------------- proj GEMM + LN2 fused: BM=128, BN=256 (full row); grid 196 ----------------
__global__ __launch_bounds__(256, 2) void projln(
    const u16* __restrict__ A, const u16* __restrict__ Bw,
    const float* __restrict__ bias, const float* __restrict__ x,
    const float* __restrict__ g2, const float* __restrict__ b2,
    float* __restrict__ out, u16* __restrict__ xn2, int rowbase)
{
  __shared__ __align__(16) u16 sA[128 * 64];
  __shared__ __align__(16) u16 sB[256 * 64];
  const int m0 = blockIdx.x * 128;
  const int tid = threadIdx.x;
  const int lane = tid & 63;
  const int wv = tid >> 6;
  const int rq = lane & 15, kg = lane >> 4;
  f32x4 acc[2][16];
  #pragma unroll
  for (int i = 0; i < 2; ++i)
    #pragma unroll
    for (int j = 0; j < 16; ++j) acc[i][j] = f32x4{0,0,0,0};

  for (int kt = 0; kt < 8; ++kt) {
    if (kt) __syncthreads();
    #pragma unroll
    for (int i = 0; i < 4; ++i) {
      const int c = i * 256 + tid;
      gload16(A + (size_t)(m0 + (c >> 3)) * 512 + kt * 64 + (c & 7) * 8, sA + c * 8);
    }
    #pragma unroll
    for (int i = 0; i < 8; ++i) {
      const int c = i * 256 + tid;
      gload16(Bw + (size_t)(c >> 3) * 512 + kt * 64 + (c & 7) * 8, sB + c * 8);
    }
    __syncthreads();
    #pragma unroll
    for (int k0 = 0; k0 < 2; ++k0) {
      short8 af[2];
      #pragma unroll
      for (int mt = 0; mt < 2; ++mt)
        af[mt] = *(const short8*)(sA + (wv * 32 + mt * 16 + rq) * 64 + k0 * 32 + kg * 8);
      #pragma unroll
      for (int nt = 0; nt < 16; ++nt) {
        const short8 bf8 = *(const short8*)(sB + (nt * 16 + rq) * 64 + k0 * 32 + kg * 8);
        #pragma unroll
        for (int mt = 0; mt < 2; ++mt)
          acc[mt][nt] = mfma16(af[mt], bf8, acc[mt][nt]);
      }
    }
  }

  float br[16], g2r[16], b2r[16];
  #pragma unroll
  for (int nt = 0; nt < 16; ++nt) {
    const int col = nt * 16 + rq;
    br[nt] = bias[col]; g2r[nt] = g2[col]; b2r[nt] = b2[col];
  }
  #pragma unroll
  for (int mt = 0; mt < 2; ++mt) {
    #pragma unroll
    for (int r = 0; r < 4; ++r) {
      const int row = m0 + wv * 32 + mt * 16 + kg * 4 + r;
      const u32 g = (u32)(rowbase + row);
      const u32 w = g / 49u; const u32 n = g - w * 49u;
      const int b = w >> 6, win = w & 63, wh = win >> 3, ww = win & 7;
      const u32 rr = n / 7u; const u32 cc = n - rr * 7u;
      int oh = wh * 7 + (int)rr + 3; if (oh >= 56) oh -= 56;
      int ow = ww * 7 + (int)cc + 3; if (ow >= 56) ow -= 56;
      const size_t po = ((size_t)b * 3136 + oh * 56 + ow) * 256;
      float vals[16];
      float s = 0.f;
      #pragma unroll
      for (int nt = 0; nt < 16; ++nt) {
        const float v = acc[mt][nt][r] + br[nt] + x[po + nt * 16 + rq];
        vals[nt] = v; s += v;
      }
      #pragma unroll
      for (int off = 1; off < 16; off <<= 1) s += __shfl_xor(s, off);
      const float mean = s * (1.0f / 256.0f);
      float sq = 0.f;
      #pragma unroll
      for (int nt = 0; nt < 16; ++nt) { const float d_ = vals[nt] - mean; sq += d_ * d_; }
      #pragma unroll
      for (int off = 1; off < 16; off <<= 1) sq += __shfl_xor(sq, off);
      const float rstd = rsqrtf(sq * (1.0f / 256.0f) + 1e-5f);
      #pragma unroll
      for (int nt = 0; nt < 16; ++nt) {
        const int col = nt * 16 + rq;
        out[po + col] = vals[nt];
        xn2[po + col] = f2bf((vals[nt] - mean) * rstd * g2r[nt] + b2r[nt]);
      }
    }
  }
}

// ---------------- fused MLP v4: asm-pinned batched weight loads, h stays in LDS ----------------
// v1 structure (8 phases x 128 h-cols, 48 KB LDS, 3 blocks/CU) + unsinkable
// volatile-asm weight loads batched 8-deep with one vmcnt(0) wait per batch.
__global__ __launch_bounds__(256, 3) void fused_mlp(
    const u16* __restrict__ xn2, const u16* __restrict__ w1,
    const float* __restrict__ bf1, const u16* __restrict__ w2,
    const float* __restrict__ bf2v, float* __restrict__ out)
{
  __shared__ __align__(16) u16 sX[64 * 256];   // 32 KB, chunk-swizzled
  __shared__ __align__(16) u16 sH[64 * 128];   // 16 KB, chunk-swizzled

  const int m0 = blockIdx.x * 64;
  const int tid = threadIdx.x;
  const int wv = tid >> 6, lane = tid & 63;
  const int rq = lane & 15, kg = lane >> 4;

  // stage xn2 panel (pre-swizzled global source, linear LDS dest)
  #pragma unroll
  for (int i = 0; i < 8; ++i) {
    const int c = i * 256 + tid;
    const int row = c >> 5, ch = c & 31;
    const int sch = (ch & 24) | ((ch ^ row) & 7);
    gload16(xn2 + (size_t)(m0 + row) * 256 + sch * 8, sX + c * 8);
  }

  f32x4 acc2[4][4];
  #pragma unroll
  for (int i = 0; i < 4; ++i)
    #pragma unroll
    for (int j = 0; j < 4; ++j) acc2[i][j] = f32x4{0,0,0,0};

  __syncthreads();

  for (int t = 0; t < 8; ++t) {
    // ---- fc1: two half-rounds; 8 asm loads in flight per round ----
    f32x4 a1[4][2];
    #pragma unroll
    for (int i = 0; i < 4; ++i)
      #pragma unroll
      for (int j = 0; j < 2; ++j) a1[i][j] = f32x4{0,0,0,0};
    #pragma unroll
    for (int half = 0; half < 2; ++half) {
      short8 wf[4][2];
      #pragma unroll
      for (int k2 = 0; k2 < 4; ++k2)
        #pragma unroll
        for (int nt = 0; nt < 2; ++nt)
          wf[k2][nt] = gload_asm(w1 + (size_t)(t * 128 + wv * 32 + nt * 16 + rq) * 256 + (half * 4 + k2) * 32 + kg * 8);
      asm volatile("s_waitcnt vmcnt(0)" ::: "memory");
      __builtin_amdgcn_sched_barrier(0);
      #pragma unroll
      for (int k2 = 0; k2 < 4; ++k2) {
        const int ks = half * 4 + k2;
        #pragma unroll
        for (int mt = 0; mt < 4; ++mt) {
          const int R = mt * 16 + rq;
          const int wk = ks * 4 + kg;
          const short8 af = *(const short8*)(sX + R * 256 + ((wk & 24) | ((wk ^ R) & 7)) * 8);
          #pragma unroll
          for (int nt = 0; nt < 2; ++nt)
            a1[mt][nt] = mfma16(af, wf[k2][nt], a1[mt][nt]);
        }
      }
    }
    __syncthreads();   // prior phase's fc2 reads of sH complete
    // ---- issue fc2 first-half loads (in flight across GELU) ----
    short8 w2f[2][4];
    #pragma unroll
    for (int p = 0; p < 2; ++p)
      #pragma unroll
      for (int nt = 0; nt < 4; ++nt)
        w2f[p][nt] = gload_asm(w2 + (size_t)(wv * 64 + nt * 16 + rq) * 1024 + t * 128 + p * 32 + kg * 8);
    // ---- bias + GELU, write h tile (swizzled) ----
    #pragma unroll
    for (int nt = 0; nt < 2; ++nt) {
      const int col = wv * 32 + nt * 16 + rq;
      const float bb = bf1[t * 128 + col];
      const int ch = col >> 3;
      #pragma unroll
      for (int mt = 0; mt < 4; ++mt)
        #pragma unroll
        for (int r = 0; r < 4; ++r) {
          const int row = mt * 16 + kg * 4 + r;
          sH[row * 128 + ((ch & 8) | ((ch ^ row) & 7)) * 8 + (col & 7)] =
              f2bf(gelu_t(a1[mt][nt][r] + bb));
        }
    }
    __syncthreads();   // h tile visible
    asm volatile("s_waitcnt vmcnt(0)" ::: "memory");
    __builtin_amdgcn_sched_barrier(0);
    // ---- fc2 first half (ks 0,1) ----
    #pragma unroll
    for (int ks = 0; ks < 2; ++ks) {
      #pragma unroll
      for (int mt = 0; mt < 4; ++mt) {
        const int R = mt * 16 + rq;
        const int wk = ks * 4 + kg;
        const short8 af = *(const short8*)(sH + R * 128 + ((wk & 8) | ((wk ^ R) & 7)) * 8);
        #pragma unroll
        for (int nt = 0; nt < 4; ++nt)
          acc2[mt][nt] = mfma16(af, w2f[ks][nt], acc2[mt][nt]);
      }
    }
    // ---- fc2 second half: load 8, wait, consume (ks 2,3) ----
    short8 w2g[2][4];
    #pragma unroll
    for (int p = 0; p < 2; ++p)
      #pragma unroll
      for (int nt = 0; nt < 4; ++nt)
        w2g[p][nt] = gload_asm(w2 + (size_t)(wv * 64 + nt * 16 + rq) * 1024 + t * 128 + (2 + p) * 32 + kg * 8);
    asm volatile("s_waitcnt vmcnt(0)" ::: "memory");
    __builtin_amdgcn_sched_barrier(0);
    #pragma unroll
    for (int ks = 0; ks < 2; ++ks) {
      #pragma unroll
      for (int mt = 0; mt < 4; ++mt) {
        const int R = mt * 16 + rq;
        const int wk = (2 + ks) * 4 + kg;
        const short8 af = *(const short8*)(sH + R * 128 + ((wk & 8) | ((wk ^ R) & 7)) * 8);
        #pragma unroll
        for (int nt = 0; nt < 4; ++nt)
          acc2[mt][nt] = mfma16(af, w2g[ks][nt], acc2[mt][nt]);
      }
    }
  }

  // ---- epilogue: + b_fc2 + residual RMW ----
  #pragma unroll
  for (int nt = 0; nt < 4; ++nt) {
    const int col = wv * 64 + nt * 16 + rq;
    const float bb = bf2v[col];
    #pragma unroll
    for (int mt = 0; mt < 4; ++mt)
      #pragma unroll
      for (int r = 0; r < 4; ++r) {
        float* p = out + (size_t)(m0 + mt * 16 + kg * 4 + r) * 256 + col;
        *p = acc2[mt][nt][r] + bb + *p;
      }
  }
}

extern "C" void kernel_launch(void* const* d_in, const int* in_sizes, int n_in,
                              void* d_out, int out_size, void* d_ws, size_t ws_size,
                              hipStream_t stream) {
  const float* x      = (const float*)d_in[0];
  const float* y      = (const float*)d_in[1];
  const float* g1     = (const float*)d_in[2];
  const float* b1     = (const float*)d_in[3];
  const float* rpb    = (const float*)d_in[4];
  const float* w_qkv  = (const float*)d_in[5];
  const float* b_qkv  = (const float*)d_in[6];
  const float* w_proj = (const float*)d_in[7];
  const float* b_proj = (const float*)d_in[8];
  const float* g2     = (const float*)d_in[9];
  const float* b2     = (const float*)d_in[10];
  const float* w_fc1  = (const float*)d_in[11];
  const float* b_fc1  = (const float*)d_in[12];
  const float* w_fc2  = (const float*)d_in[13];
  const float* b_fc2  = (const float*)d_in[14];
  float* out = (float*)d_out;

  u16* wsp = (u16*)d_ws;
  u16* wqkv_bf  = wsp;                       //  786432
  u16* wproj_bf = wsp + 786432;              //  131072
  u16* wfc1_bf  = wsp + 917504;              //  262144
  u16* wfc2_bf  = wsp + 1179648;             //  262144
  float* btab   = (float*)(wsp + 1441792);   //  131072 f32
  u16* xn2      = wsp + 1703936;             //  25690112
  u16* XYc      = wsp + 27394048;            //  12845056 (25088 x 512)
  u16* qkvc     = wsp + 40239104;            //  24 planes x 25088 x 64

  convk<<<768, 256, 0, stream>>>(w_qkv,  wqkv_bf,  196608);
  convk<<<128, 256, 0, stream>>>(w_proj, wproj_bf, 32768);
  convk<<<256, 256, 0, stream>>>(w_fc1,  wfc1_bf,  65536);
  convk<<<256, 256, 0, stream>>>(w_fc2,  wfc2_bf,  65536);
  btab_build<<<32, 256, 0, stream>>>(rpb, btab);

  for (int c = 0; c < 4; ++c) {
    ln_gather<<<6272, 256, 0, stream>>>(x, y, g1, b1, XYc, c * CHUNK_ROWS);
    qkv_gemm<<<dim3(12, 196), 256, 0, stream>>>(XYc, wqkv_bf, b_qkv, qkvc);
    attn3<<<1024, 256, 0, stream>>>(qkvc, btab, XYc, c * 512);
    projln<<<196, 256, 0, stream>>>(XYc, wproj_bf, b_proj, x, g2, b2, out, xn2, c * CHUNK_ROWS);
  }

  fused_mlp<<<1568, 256, 0, stream>>>(xn2, wfc1_bf, b_fc1, wfc2_bf, b_fc2, out);
}

// Round 12
// 844.272 us; speedup vs baseline: 1.0758x; 1.0616x over previous
//
#include <hip/hip_runtime.h>
#include <hip/hip_bf16.h>

#define DEVI __device__ __forceinline__

typedef __attribute__((ext_vector_type(8))) short short8;
typedef __attribute__((ext_vector_type(4))) float f32x4;
typedef unsigned int u32;
typedef unsigned short u16;

typedef __attribute__((address_space(1))) const u32 gu32_t;
typedef __attribute__((address_space(3))) u32 lu32_t;

DEVI u16 f2bf(float f) {
  u32 u = __builtin_bit_cast(u32, f);
  u32 r = (u + 0x7fffu + ((u >> 16) & 1u)) >> 16;
  return (u16)r;
}

DEVI f32x4 mfma16(short8 a, short8 b, f32x4 c) {
  return __builtin_amdgcn_mfma_f32_16x16x32_bf16(a, b, c, 0, 0, 0);
}

DEVI void gload16(const void* g, void* l) {
  __builtin_amdgcn_global_load_lds((gu32_t*)g, (lu32_t*)l, 16, 0, 0);
}

DEVI float gelu_t(float v) {
  const float u = v * (0.7978845608f + 0.0356774081f * v * v);
  const float t = 1.0f - 2.0f / (__expf(2.0f * u) + 1.0f);
  return 0.5f * v * (1.0f + t);
}

#define CHUNK_ROWS 25088   // 512 windows * 49 tokens
#define PLANE ((size_t)CHUNK_ROWS * 64)
#define KOFF  ((size_t)8 * PLANE)          // k planes base
#define VOFF  ((size_t)16 * PLANE)         // v planes base (linear)

// ---------------- all weights f32 -> bf16, one launch ----------------
__global__ __launch_bounds__(256) void convall(
    const float* __restrict__ wq, const float* __restrict__ wp,
    const float* __restrict__ w1, const float* __restrict__ w2,
    u16* __restrict__ dq, u16* __restrict__ dp, u16* __restrict__ d1, u16* __restrict__ d2)
{
  const int i = blockIdx.x * 256 + threadIdx.x;   // global float4 index, 0..360447
  const float* s; u16* d; int off;
  if (i < 196608)      { s = wq; d = dq; off = i; }
  else if (i < 229376) { s = wp; d = dp; off = i - 196608; }
  else if (i < 294912) { s = w1; d = d1; off = i - 229376; }
  else                 { s = w2; d = d2; off = i - 294912; }
  const float4 v = ((const float4*)s)[off];
  ushort4 o;
  o.x = f2bf(v.x); o.y = f2bf(v.y); o.z = f2bf(v.z); o.w = f2bf(v.w);
  ((ushort4*)d)[off] = o;
}

// ---------------- fused bias+mask+pad table: [4 cls][8 h][64 n][64 m] f32 ----------------
__global__ __launch_bounds__(256) void btab_build(const float* __restrict__ rpb, float* __restrict__ btab) {
  const int cls = blockIdx.x >> 3, h = blockIdx.x & 7;
  float* dst = btab + (size_t)(cls * 8 + h) * 4096;
  for (int e = threadIdx.x; e < 4096; e += 256) {
    const int n = e >> 6, m = e & 63;
    float v;
    if (m >= 49) {
      v = -1e30f;
    } else if (n >= 49) {
      v = 0.f;
    } else {
      const int r1 = n / 7, c1 = n - r1 * 7;
      const int r2 = m / 7, c2 = m - r2 * 7;
      const int rel = (r1 - r2 + 6) * 13 + (c1 - c2 + 6);
      v = rpb[rel * 8 + h];
      const int reg1 = ((cls & 1) ? (r1 < 4 ? 1 : 2) : 0) * 3 + ((cls & 2) ? (c1 < 4 ? 1 : 2) : 0);
      const int reg2 = ((cls & 1) ? (r2 < 4 ? 1 : 2) : 0) * 3 + ((cls & 2) ? (c2 < 4 ? 1 : 2) : 0);
      if (reg1 != reg2) v -= 100.f;
    }
    dst[e] = v;
  }
}

// ---------------- LN1 + shift + window gather -> XY bf16 [CHUNK_ROWS][512] ----------------
__global__ __launch_bounds__(256) void ln_gather(
    const float* __restrict__ x, const float* __restrict__ y,
    const float* __restrict__ g1, const float* __restrict__ b1,
    u16* __restrict__ XY, int rowbase)
{
  const int wv = threadIdx.x >> 6, lane = threadIdx.x & 63;
  const int rl = blockIdx.x * 4 + wv;
  const int row = rowbase + rl;
  const int w = row / 49, n = row - w * 49;
  const int b = w >> 6, win = w & 63, wh = win >> 3, ww = win & 7;
  const int r = n / 7, c = n - r * 7;
  int oh = wh * 7 + r + 3; if (oh >= 56) oh -= 56;
  int ow = ww * 7 + c + 3; if (ow >= 56) ow -= 56;
  const size_t po = ((size_t)b * 3136 + oh * 56 + ow) * 256;
  const float4 g1v = ((const float4*)g1)[lane];
  const float4 b1v = ((const float4*)b1)[lane];
  u16* orow = XY + (size_t)rl * 512;
  #pragma unroll
  for (int mod = 0; mod < 2; ++mod) {
    const float* src = (mod ? y : x) + po;
    const float4 v = ((const float4*)src)[lane];
    float s = v.x + v.y + v.z + v.w;
    #pragma unroll
    for (int off = 1; off < 64; off <<= 1) s += __shfl_xor(s, off);
    const float mean = s * (1.0f / 256.0f);
    const float d0 = v.x - mean, d1 = v.y - mean, d2 = v.z - mean, d3 = v.w - mean;
    float sq = d0 * d0 + d1 * d1 + d2 * d2 + d3 * d3;
    #pragma unroll
    for (int off = 1; off < 64; off <<= 1) sq += __shfl_xor(sq, off);
    const float rstd = rsqrtf(sq * (1.0f / 256.0f) + 1e-5f);
    ushort4 o;
    o.x = f2bf(d0 * rstd * g1v.x + b1v.x);
    o.y = f2bf(d1 * rstd * g1v.y + b1v.y);
    o.z = f2bf(d2 * rstd * g1v.z + b1v.z);
    o.w = f2bf(d3 * rstd * g1v.w + b1v.w);
    *(ushort4*)(orow + mod * 256 + lane * 4) = o;
  }
}

// ---------------- QKV GEMM (128x128, XCD-swizzled): M=25088, N=1536, K=512 ----------------
// C-tile routed through LDS (overlay of sA/sB) -> coalesced b128 stores per head.
__global__ __launch_bounds__(256) void qkv_gemm(
    const u16* __restrict__ A, const u16* __restrict__ Bw,
    const float* __restrict__ bias, u16* __restrict__ Qo)
{
  __shared__ __align__(16) u16 smem[128 * 128];   // 32 KB: sA|sB during K loop, C-tile after
  u16* sA = smem;
  u16* sB = smem + 128 * 64;
  const int nx = gridDim.x;
  const int nwg = nx * gridDim.y;
  const int orig = blockIdx.y * nx + blockIdx.x;
  const int sw = (orig & 7) * (nwg >> 3) + (orig >> 3);
  const int m0  = (sw / nx) * 128;
  const int nn0 = (sw % nx) * 128;
  const int tid = threadIdx.x;
  const int lane = tid & 63;
  const int wv = tid >> 6;
  const int wm = wv >> 1, wn = wv & 1;
  const int rq = lane & 15, kg = lane >> 4;
  f32x4 acc[4][4];
  #pragma unroll
  for (int i = 0; i < 4; ++i)
    #pragma unroll
    for (int j = 0; j < 4; ++j) acc[i][j] = f32x4{0,0,0,0};

  for (int kt = 0; kt < 8; ++kt) {
    if (kt) __syncthreads();
    #pragma unroll
    for (int i = 0; i < 4; ++i) {
      const int c = i * 256 + tid;
      gload16(A + (size_t)(m0 + (c >> 3)) * 512 + kt * 64 + (c & 7) * 8, sA + c * 8);
    }
    #pragma unroll
    for (int i = 0; i < 4; ++i) {
      const int c = i * 256 + tid;
      gload16(Bw + (size_t)(nn0 + (c >> 3)) * 512 + kt * 64 + (c & 7) * 8, sB + c * 8);
    }
    __syncthreads();
    #pragma unroll
    for (int k0 = 0; k0 < 2; ++k0) {
      short8 af[4], bf8[4];
      #pragma unroll
      for (int mt = 0; mt < 4; ++mt)
        af[mt] = *(const short8*)(sA + (wm * 64 + mt * 16 + rq) * 64 + k0 * 32 + kg * 8);
      #pragma unroll
      for (int nt = 0; nt < 4; ++nt)
        bf8[nt] = *(const short8*)(sB + (wn * 64 + nt * 16 + rq) * 64 + k0 * 32 + kg * 8);
      #pragma unroll
      for (int mt = 0; mt < 4; ++mt)
        #pragma unroll
        for (int nt = 0; nt < 4; ++nt)
          acc[mt][nt] = mfma16(af[mt], bf8[nt], acc[mt][nt]);
    }
  }
  // ---- C tile -> LDS (swizzled), then coalesced stores ----
  __syncthreads();
  const int t = nn0 >> 9;
  const int hbase = (nn0 & 511) >> 6;
  const float sc = (t == 0) ? 0.17677669529663687f : 1.0f;
  #pragma unroll
  for (int nt = 0; nt < 4; ++nt) {
    const int col = wn * 64 + nt * 16 + rq;           // local 0..127
    const float bc = bias[nn0 + col];
    const int c = col >> 3;
    #pragma unroll
    for (int mt = 0; mt < 4; ++mt)
      #pragma unroll
      for (int r = 0; r < 4; ++r) {
        const int row = wm * 64 + mt * 16 + kg * 4 + r;  // local 0..127
        smem[row * 128 + (((c & 8) | ((c ^ row) & 7)) << 3) + (col & 7)] =
            f2bf((acc[mt][nt][r] + bc) * sc);
      }
  }
  __syncthreads();
  #pragma unroll
  for (int it = 0; it < 8; ++it) {
    const int cc = it * 256 + tid;
    const int row = cc >> 4, c = cc & 15;
    const int col = c * 8;
    const int hh = col >> 6, d = col & 63;
    const short8 v = *(const short8*)(smem + row * 128 + (((c & 8) | ((c ^ row) & 7)) << 3));
    *(short8*)(Qo + (size_t)(t * 8 + hbase + hh) * PLANE + (size_t)(m0 + row) * 64 + d) = v;
  }
}

// ---------------- barrier-free attention: one wave per (window, head), table-driven softmax ----------------
// 128-thread blocks (2 waves) -> 31 KB LDS -> 5 blocks/CU (10 waves) for latency hiding.
__global__ __launch_bounds__(128, 3) void attn3(
    const u16* __restrict__ qkv, const float* __restrict__ btab,
    u16* __restrict__ concat, int wbase)
{
  __shared__ __align__(16) u16 sP[2][3136];    // per-wave P / out buffer (49 x 64, swizzled)
  __shared__ __align__(16) u16 sVT[2][4608];   // per-wave vT: [d][tok^((d>>3)&3)<<4], stride 72

  const int tid = threadIdx.x;
  const int wv = tid >> 6, lane = tid & 63;
  const int rq = lane & 15, kg = lane >> 4;
  const int gw = blockIdx.x * 2 + wv;
  const int wl = gw >> 3, h = gw & 7;
  const int w = wbase + wl;
  const int win = w & 63, wh = win >> 3, ww = win & 7;
  const int cls = ((wh == 7) ? 1 : 0) | ((ww == 7) ? 2 : 0);
  const float* Tb = btab + (size_t)(cls * 8 + h) * 4096;
  u16* sPw = sP[wv];
  u16* sVw = sVT[wv];

  const u16* qbase = qkv + (size_t)h * PLANE + (size_t)wl * 49 * 64;
  const u16* kbase = qkv + KOFF + (size_t)h * PLANE + (size_t)wl * 49 * 64;
  const u16* vbase = qkv + VOFF + (size_t)h * PLANE + (size_t)wl * 49 * 64;

  // ---- issue v row loads early (hidden under QK^T) ----
  short8 vreg[4][2];
  #pragma unroll
  for (int t = 0; t < 4; ++t)
    #pragma unroll
    for (int h2 = 0; h2 < 2; ++h2)
      vreg[t][h2] = *(const short8*)(vbase + (size_t)(16 * t + rq) * 64 + kg * 8 + h2 * 32);

  // ---- K fragments (all), then S with per-i Q loads ----
  short8 ak[4][2];
  #pragma unroll
  for (int j = 0; j < 4; ++j) {
    const int rr = (16 * j + rq) > 48 ? 48 : (16 * j + rq);
    ak[j][0] = *(const short8*)(kbase + rr * 64 + kg * 8);
    ak[j][1] = *(const short8*)(kbase + rr * 64 + 32 + kg * 8);
  }
  f32x4 sacc[4][4];
  #pragma unroll
  for (int i = 0; i < 4; ++i)
    #pragma unroll
    for (int j = 0; j < 4; ++j) sacc[i][j] = f32x4{0,0,0,0};
  #pragma unroll
  for (int i = 0; i < 4; ++i) {
    const int rr = (16 * i + rq) > 48 ? 48 : (16 * i + rq);
    const short8 a0 = *(const short8*)(qbase + rr * 64 + kg * 8);
    const short8 a1 = *(const short8*)(qbase + rr * 64 + 32 + kg * 8);
    #pragma unroll
    for (int j = 0; j < 4; ++j) {
      sacc[i][j] = mfma16(a0, ak[j][0], sacc[i][j]);
      sacc[i][j] = mfma16(a1, ak[j][1], sacc[i][j]);
    }
  }

  // ---- write v into LDS vT (conflict-free: row ^ (kg<<4)) ----
  #pragma unroll
  for (int t = 0; t < 4; ++t) {
    const int row = 16 * t + rq;
    #pragma unroll
    for (int h2 = 0; h2 < 2; ++h2) {
      const int c0 = kg * 8 + h2 * 32;
      #pragma unroll
      for (int j = 0; j < 8; ++j)
        sVw[(c0 + j) * 72 + (row ^ (kg << 4))] = (u16)vreg[t][h2][j];
    }
  }

  // ---- table-driven softmax; P -> sPw (swizzled) ----
  #pragma unroll
  for (int i = 0; i < 4; ++i) {
    #pragma unroll
    for (int r = 0; r < 4; ++r) {
      const int n = 16 * i + kg * 4 + r;
      const float* Trow = Tb + n * 64 + rq;
      float pv[4];
      #pragma unroll
      for (int j = 0; j < 4; ++j)
        pv[j] = sacc[i][j][r] + Trow[16 * j];
      float mx = fmaxf(fmaxf(pv[0], pv[1]), fmaxf(pv[2], pv[3]));
      #pragma unroll
      for (int off = 1; off < 16; off <<= 1) mx = fmaxf(mx, __shfl_xor(mx, off));
      float sm = 0.f;
      #pragma unroll
      for (int j = 0; j < 4; ++j) { const float e = __expf(pv[j] - mx); pv[j] = e; sm += e; }
      #pragma unroll
      for (int off = 1; off < 16; off <<= 1) sm += __shfl_xor(sm, off);
      const float inv = 1.0f / sm;
      if (n < 49) {
        #pragma unroll
        for (int j = 0; j < 4; ++j) {
          const int col = 16 * j + rq;
          sPw[n * 64 + (((col >> 3) ^ (n & 7)) << 3) + (col & 7)] = f2bf(pv[j] * inv);
        }
      }
    }
  }

  // ---- PV: A = P (LDS), B = vT (LDS b128, pad toks masked) ----
  f32x4 oacc[4][4];
  #pragma unroll
  for (int i = 0; i < 4; ++i)
    #pragma unroll
    for (int j = 0; j < 4; ++j) oacc[i][j] = f32x4{0,0,0,0};
  #pragma unroll
  for (int m0v = 0; m0v < 2; ++m0v) {
    short8 av[4];
    #pragma unroll
    for (int ct = 0; ct < 4; ++ct) {
      const int col = ct * 16 + rq;
      const int s = (col >> 3) & 3;
      short8 vvv = *(const short8*)(sVw + col * 72 + ((m0v * 32 + kg * 8) ^ (s << 4)));
      if (m0v == 1) {
        if (kg == 3) {
          #pragma unroll
          for (int e = 0; e < 8; ++e) vvv[e] = 0;
        } else if (kg == 2) {
          #pragma unroll
          for (int e = 1; e < 8; ++e) vvv[e] = 0;
        }
      }
      av[ct] = vvv;
    }
    #pragma unroll
    for (int i = 0; i < 4; ++i) {
      const int rr = (16 * i + rq) > 48 ? 48 : (16 * i + rq);
      const int ch = (m0v * 4 + kg) ^ (rr & 7);
      const short8 pa = *(const short8*)(sPw + rr * 64 + ch * 8);
      #pragma unroll
      for (int ct = 0; ct < 4; ++ct)
        oacc[i][ct] = mfma16(pa, av[ct], oacc[i][ct]);
    }
  }

  // ---- repack out_h through LDS (reuse sPw), coalesced b128 store ----
  __builtin_amdgcn_s_waitcnt(0);
  #pragma unroll
  for (int i = 0; i < 4; ++i)
    #pragma unroll
    for (int ct = 0; ct < 4; ++ct)
      #pragma unroll
      for (int r = 0; r < 4; ++r) {
        const int n = 16 * i + kg * 4 + r;
        if (n < 49) {
          const int col = ct * 16 + rq;
          sPw[n * 64 + (((col >> 3) ^ (n & 7)) << 3) + (col & 7)] = f2bf(oacc[i][ct][r]);
        }
      }
  u16* crow = concat + (size_t)(wl * 49) * 512 + h * 64;
  #pragma unroll
  for (int it = 0; it < 7; ++it) {
    const int c = it * 64 + lane;
    if (c < 392) {
      const int m = c >> 3, s = c & 7;
      const short8 vvv = *(const short8*)(sPw + m * 64 + ((s ^ (m & 7)) << 3));
      *(short8*)(crow + (size_t)m * 512 + s * 8) = vvv;
    }
  }
}

// ---------------- proj GEMM + LN2 fused: BM=64, BN=256 (full row); grid 392 ----------------
__global__ __launch_bounds__(256, 3) void projln(
    const u16* __restrict__ A, const u16* __restrict__ Bw,
    const float* __restrict__ bias, const float* __restrict__ x,
    const float* __restrict__ g2, const float* __restrict__ b2,
    float* __restrict__ out, u16* __restrict__ xn2, int rowbase)
{
  __shared__ __align__(16) u16 sA[64 * 64];
  __shared__ __align__(16) u16 sB[256 * 64];
  const int m0 = blockIdx.x * 64;
  const int tid = threadIdx.x;
  const int lane = tid & 63;
  const int wv = tid >> 6;
  const int rq = lane & 15, kg = lane >> 4;
  f32x4 acc[16];
  #pragma unroll
  for (int j = 0; j < 16; ++j) acc[j] = f32x4{0,0,0,0};

  for (int kt = 0; kt < 8; ++kt) {
    if (kt) __syncthreads();
    #pragma unroll
    for (int i = 0; i < 2; ++i) {
      const int c = i * 256 + tid;
      gload16(A + (size_t)(m0 + (c >> 3)) * 512 + kt * 64 + (c & 7) * 8, sA + c * 8);
    }
    #pragma unroll
    for (int i = 0; i < 8; ++i) {
      const int c = i * 256 + tid;
      gload16(Bw + (size_t)(c >> 3) * 512 + kt * 64 + (c & 7) * 8, sB + c * 8);
    }
    __syncthreads();
    #pragma unroll
    for (int k0 = 0; k0 < 2; ++k0) {
      const short8 af = *(const short8*)(sA + (wv * 16 + rq) * 64 + k0 * 32 + kg * 8);
      #pragma unroll
      for (int nt = 0; nt < 16; ++nt) {
        const short8 bf8 = *(const short8*)(sB + (nt * 16 + rq) * 64 + k0 * 32 + kg * 8);
        acc[nt] = mfma16(af, bf8, acc[nt]);
      }
    }
  }

  float br[16], g2r[16], b2r[16];
  #pragma unroll
  for (int nt = 0; nt < 16; ++nt) {
    const int col = nt * 16 + rq;
    br[nt] = bias[col]; g2r[nt] = g2[col]; b2r[nt] = b2[col];
  }
  #pragma unroll
  for (int r = 0; r < 4; ++r) {
    const int row = m0 + wv * 16 + kg * 4 + r;
    const u32 g = (u32)(rowbase + row);
    const u32 w = g / 49u; const u32 n = g - w * 49u;
    const int b = w >> 6, win = w & 63, wh = win >> 3, ww = win & 7;
    const u32 rr = n / 7u; const u32 cc = n - rr * 7u;
    int oh = wh * 7 + (int)rr + 3; if (oh >= 56) oh -= 56;
    int ow = ww * 7 + (int)cc + 3; if (ow >= 56) ow -= 56;
    const size_t po = ((size_t)b * 3136 + oh * 56 + ow) * 256;
    float vals[16];
    float s = 0.f;
    #pragma unroll
    for (int nt = 0; nt < 16; ++nt) {
      const float v = acc[nt][r] + br[nt] + x[po + nt * 16 + rq];
      vals[nt] = v; s += v;
    }
    #pragma unroll
    for (int off = 1; off < 16; off <<= 1) s += __shfl_xor(s, off);
    const float mean = s * (1.0f / 256.0f);
    float sq = 0.f;
    #pragma unroll
    for (int nt = 0; nt < 16; ++nt) { const float d_ = vals[nt] - mean; sq += d_ * d_; }
    #pragma unroll
    for (int off = 1; off < 16; off <<= 1) sq += __shfl_xor(sq, off);
    const float rstd = rsqrtf(sq * (1.0f / 256.0f) + 1e-5f);
    #pragma unroll
    for (int nt = 0; nt < 16; ++nt) {
      const int col = nt * 16 + rq;
      out[po + col] = vals[nt];
      xn2[po + col] = f2bf((vals[nt] - mean) * rstd * g2r[nt] + b2r[nt]);
    }
  }
}

// ---------------- fused MLP (R8 v1, best known): fc1+GELU+fc2+residual, h in LDS ----------------
__global__ __launch_bounds__(256, 3) void fused_mlp(
    const u16* __restrict__ xn2, const u16* __restrict__ w1,
    const float* __restrict__ bf1, const u16* __restrict__ w2,
    const float* __restrict__ bf2v, float* __restrict__ out)
{
  __shared__ __align__(16) u16 sX[64 * 256];   // xn2 panel, chunk-swizzled
  __shared__ __align__(16) u16 sH[64 * 128];   // h tile, chunk-swizzled

  const int m0 = blockIdx.x * 64;
  const int tid = threadIdx.x;
  const int wv = tid >> 6, lane = tid & 63;
  const int rq = lane & 15, kg = lane >> 4;

  // stage xn2 panel (pre-swizzled global source, linear LDS dest)
  #pragma unroll
  for (int i = 0; i < 8; ++i) {
    const int c = i * 256 + tid;
    const int row = c >> 5, ch = c & 31;
    const int sch = (ch & 24) | ((ch ^ row) & 7);
    gload16(xn2 + (size_t)(m0 + row) * 256 + sch * 8, sX + c * 8);
  }

  f32x4 acc2[4][4];
  #pragma unroll
  for (int i = 0; i < 4; ++i)
    #pragma unroll
    for (int j = 0; j < 4; ++j) acc2[i][j] = f32x4{0,0,0,0};

  __syncthreads();

  for (int t = 0; t < 8; ++t) {
    // ---- fc1: this wave's 32 h-cols of tile t ----
    f32x4 a1[4][2];
    #pragma unroll
    for (int i = 0; i < 4; ++i)
      #pragma unroll
      for (int j = 0; j < 2; ++j) a1[i][j] = f32x4{0,0,0,0};
    #pragma unroll
    for (int ks = 0; ks < 8; ++ks) {
      short8 bfr[2];
      #pragma unroll
      for (int nt = 0; nt < 2; ++nt)
        bfr[nt] = *(const short8*)(w1 + (size_t)(t * 128 + wv * 32 + nt * 16 + rq) * 256 + ks * 32 + kg * 8);
      #pragma unroll
      for (int mt = 0; mt < 4; ++mt) {
        const int R = mt * 16 + rq;
        const int wk = ks * 4 + kg;
        const short8 af = *(const short8*)(sX + R * 256 + ((wk & 24) | ((wk ^ R) & 7)) * 8);
        #pragma unroll
        for (int nt = 0; nt < 2; ++nt)
          a1[mt][nt] = mfma16(af, bfr[nt], a1[mt][nt]);
      }
    }
    __syncthreads();   // previous tile's fc2 reads of sH complete
    // ---- bias + GELU, write h tile (swizzled) ----
    #pragma unroll
    for (int nt = 0; nt < 2; ++nt) {
      const int col = wv * 32 + nt * 16 + rq;
      const float bb = bf1[t * 128 + col];
      const int ch = col >> 3;
      #pragma unroll
      for (int mt = 0; mt < 4; ++mt)
        #pragma unroll
        for (int r = 0; r < 4; ++r) {
          const int row = mt * 16 + kg * 4 + r;
          sH[row * 128 + ((ch & 8) | ((ch ^ row) & 7)) * 8 + (col & 7)] =
              f2bf(gelu_t(a1[mt][nt][r] + bb));
        }
    }
    __syncthreads();   // h tile visible
    // ---- fc2 partial: all 64 rows x this wave's 64 cols, k = t*128..+128 ----
    #pragma unroll
    for (int ks = 0; ks < 4; ++ks) {
      short8 bfr2[4];
      #pragma unroll
      for (int nt = 0; nt < 4; ++nt)
        bfr2[nt] = *(const short8*)(w2 + (size_t)(wv * 64 + nt * 16 + rq) * 1024 + t * 128 + ks * 32 + kg * 8);
      #pragma unroll
      for (int mt = 0; mt < 4; ++mt) {
        const int R = mt * 16 + rq;
        const int wk = ks * 4 + kg;
        const short8 af = *(const short8*)(sH + R * 128 + ((wk & 8) | ((wk ^ R) & 7)) * 8);
        #pragma unroll
        for (int nt = 0; nt < 4; ++nt)
          acc2[mt][nt] = mfma16(af, bfr2[nt], acc2[mt][nt]);
      }
    }
  }

  // ---- epilogue: + b_fc2 + residual RMW ----
  #pragma unroll
  for (int nt = 0; nt < 4; ++nt) {
    const int col = wv * 64 + nt * 16 + rq;
    const float bb = bf2v[col];
    #pragma unroll
    for (int mt = 0; mt < 4; ++mt)
      #pragma unroll
      for (int r = 0; r < 4; ++r) {
        float* p = out + (size_t)(m0 + mt * 16 + kg * 4 + r) * 256 + col;
        *p = acc2[mt][nt][r] + bb + *p;
      }
  }
}

extern "C" void kernel_launch(void* const* d_in, const int* in_sizes, int n_in,
                              void* d_out, int out_size, void* d_ws, size_t ws_size,
                              hipStream_t stream) {
  const float* x      = (const float*)d_in[0];
  const float* y      = (const float*)d_in[1];
  const float* g1     = (const float*)d_in[2];
  const float* b1     = (const float*)d_in[3];
  const float* rpb    = (const float*)d_in[4];
  const float* w_qkv  = (const float*)d_in[5];
  const float* b_qkv  = (const float*)d_in[6];
  const float* w_proj = (const float*)d_in[7];
  const float* b_proj = (const float*)d_in[8];
  const float* g2     = (const float*)d_in[9];
  const float* b2     = (const float*)d_in[10];
  const float* w_fc1  = (const float*)d_in[11];
  const float* b_fc1  = (const float*)d_in[12];
  const float* w_fc2  = (const float*)d_in[13];
  const float* b_fc2  = (const float*)d_in[14];
  float* out = (float*)d_out;

  u16* wsp = (u16*)d_ws;
  u16* wqkv_bf  = wsp;                       //  786432
  u16* wproj_bf = wsp + 786432;              //  131072
  u16* wfc1_bf  = wsp + 917504;              //  262144
  u16* wfc2_bf  = wsp + 1179648;             //  262144
  float* btab   = (float*)(wsp + 1441792);   //  131072 f32
  u16* xn2      = wsp + 1703936;             //  25690112
  u16* XYc      = wsp + 27394048;            //  12845056 (25088 x 512)
  u16* qkvc     = wsp + 40239104;            //  24 planes x 25088 x 64

  convall<<<1408, 256, 0, stream>>>(w_qkv, w_proj, w_fc1, w_fc2,
                                    wqkv_bf, wproj_bf, wfc1_bf, wfc2_bf);
  btab_build<<<32, 256, 0, stream>>>(rpb, btab);

  for (int c = 0; c < 4; ++c) {
    ln_gather<<<6272, 256, 0, stream>>>(x, y, g1, b1, XYc, c * CHUNK_ROWS);
    qkv_gemm<<<dim3(12, 196), 256, 0, stream>>>(XYc, wqkv_bf, b_qkv, qkvc);
    attn3<<<2048, 128, 0, stream>>>(qkvc, btab, XYc, c * 512);
    projln<<<392, 256, 0, stream>>>(XYc, wproj_bf, b_proj, x, g2, b2, out, xn2, c * CHUNK_ROWS);
  }

  fused_mlp<<<1568, 256, 0, stream>>>(xn2, wfc1_bf, b_fc1, wfc2_bf, b_fc2, out);
}

// Round 13
// 842.333 us; speedup vs baseline: 1.0782x; 1.0023x over previous
//
#include <hip/hip_runtime.h>
#include <hip/hip_bf16.h>

#define DEVI __device__ __forceinline__

typedef __attribute__((ext_vector_type(8))) short short8;
typedef __attribute__((ext_vector_type(4))) float f32x4;
typedef unsigned int u32;
typedef unsigned short u16;

typedef __attribute__((address_space(1))) const u32 gu32_t;
typedef __attribute__((address_space(3))) u32 lu32_t;

DEVI u16 f2bf(float f) {
  u32 u = __builtin_bit_cast(u32, f);
  u32 r = (u + 0x7fffu + ((u >> 16) & 1u)) >> 16;
  return (u16)r;
}

DEVI f32x4 mfma16(short8 a, short8 b, f32x4 c) {
  return __builtin_amdgcn_mfma_f32_16x16x32_bf16(a, b, c, 0, 0, 0);
}

DEVI void gload16(const void* g, void* l) {
  __builtin_amdgcn_global_load_lds((gu32_t*)g, (lu32_t*)l, 16, 0, 0);
}

DEVI float gelu_t(float v) {
  const float u = v * (0.7978845608f + 0.0356774081f * v * v);
  const float t = 1.0f - 2.0f / (__expf(2.0f * u) + 1.0f);
  return 0.5f * v * (1.0f + t);
}

#define CHUNK_ROWS 25088   // 512 windows * 49 tokens
#define PLANE ((size_t)CHUNK_ROWS * 64)
#define KOFF  ((size_t)8 * PLANE)          // k planes base
#define VOFF  ((size_t)16 * PLANE)         // v planes base (linear)

// ---------------- all weights f32 -> bf16, one launch ----------------
__global__ __launch_bounds__(256) void convall(
    const float* __restrict__ wq, const float* __restrict__ wp,
    const float* __restrict__ w1, const float* __restrict__ w2,
    u16* __restrict__ dq, u16* __restrict__ dp, u16* __restrict__ d1, u16* __restrict__ d2)
{
  const int i = blockIdx.x * 256 + threadIdx.x;   // global float4 index, 0..360447
  const float* s; u16* d; int off;
  if (i < 196608)      { s = wq; d = dq; off = i; }
  else if (i < 229376) { s = wp; d = dp; off = i - 196608; }
  else if (i < 294912) { s = w1; d = d1; off = i - 229376; }
  else                 { s = w2; d = d2; off = i - 294912; }
  const float4 v = ((const float4*)s)[off];
  ushort4 o;
  o.x = f2bf(v.x); o.y = f2bf(v.y); o.z = f2bf(v.z); o.w = f2bf(v.w);
  ((ushort4*)d)[off] = o;
}

// ---------------- fused bias+mask+pad table: [4 cls][8 h][64 n][64 m] f32 ----------------
__global__ __launch_bounds__(256) void btab_build(const float* __restrict__ rpb, float* __restrict__ btab) {
  const int cls = blockIdx.x >> 3, h = blockIdx.x & 7;
  float* dst = btab + (size_t)(cls * 8 + h) * 4096;
  for (int e = threadIdx.x; e < 4096; e += 256) {
    const int n = e >> 6, m = e & 63;
    float v;
    if (m >= 49) {
      v = -1e30f;
    } else if (n >= 49) {
      v = 0.f;
    } else {
      const int r1 = n / 7, c1 = n - r1 * 7;
      const int r2 = m / 7, c2 = m - r2 * 7;
      const int rel = (r1 - r2 + 6) * 13 + (c1 - c2 + 6);
      v = rpb[rel * 8 + h];
      const int reg1 = ((cls & 1) ? (r1 < 4 ? 1 : 2) : 0) * 3 + ((cls & 2) ? (c1 < 4 ? 1 : 2) : 0);
      const int reg2 = ((cls & 1) ? (r2 < 4 ? 1 : 2) : 0) * 3 + ((cls & 2) ? (c2 < 4 ? 1 : 2) : 0);
      if (reg1 != reg2) v -= 100.f;
    }
    dst[e] = v;
  }
}

// ---------------- LN1 + shift + window gather -> XY bf16 [CHUNK_ROWS][512] ----------------
__global__ __launch_bounds__(256) void ln_gather(
    const float* __restrict__ x, const float* __restrict__ y,
    const float* __restrict__ g1, const float* __restrict__ b1,
    u16* __restrict__ XY, int rowbase)
{
  const int wv = threadIdx.x >> 6, lane = threadIdx.x & 63;
  const int rl = blockIdx.x * 4 + wv;
  const int row = rowbase + rl;
  const int w = row / 49, n = row - w * 49;
  const int b = w >> 6, win = w & 63, wh = win >> 3, ww = win & 7;
  const int r = n / 7, c = n - r * 7;
  int oh = wh * 7 + r + 3; if (oh >= 56) oh -= 56;
  int ow = ww * 7 + c + 3; if (ow >= 56) ow -= 56;
  const size_t po = ((size_t)b * 3136 + oh * 56 + ow) * 256;
  const float4 g1v = ((const float4*)g1)[lane];
  const float4 b1v = ((const float4*)b1)[lane];
  u16* orow = XY + (size_t)rl * 512;
  #pragma unroll
  for (int mod = 0; mod < 2; ++mod) {
    const float* src = (mod ? y : x) + po;
    const float4 v = ((const float4*)src)[lane];
    float s = v.x + v.y + v.z + v.w;
    #pragma unroll
    for (int off = 1; off < 64; off <<= 1) s += __shfl_xor(s, off);
    const float mean = s * (1.0f / 256.0f);
    const float d0 = v.x - mean, d1 = v.y - mean, d2 = v.z - mean, d3 = v.w - mean;
    float sq = d0 * d0 + d1 * d1 + d2 * d2 + d3 * d3;
    #pragma unroll
    for (int off = 1; off < 64; off <<= 1) sq += __shfl_xor(sq, off);
    const float rstd = rsqrtf(sq * (1.0f / 256.0f) + 1e-5f);
    ushort4 o;
    o.x = f2bf(d0 * rstd * g1v.x + b1v.x);
    o.y = f2bf(d1 * rstd * g1v.y + b1v.y);
    o.z = f2bf(d2 * rstd * g1v.z + b1v.z);
    o.w = f2bf(d3 * rstd * g1v.w + b1v.w);
    *(ushort4*)(orow + mod * 256 + lane * 4) = o;
  }
}

// ---------------- QKV GEMM (128x128, XCD-swizzled): M=25088, N=1536, K=512 ----------------
// C-tile routed through LDS (overlay of sA/sB) -> coalesced b128 stores per head.
__global__ __launch_bounds__(256) void qkv_gemm(
    const u16* __restrict__ A, const u16* __restrict__ Bw,
    const float* __restrict__ bias, u16* __restrict__ Qo)
{
  __shared__ __align__(16) u16 smem[128 * 128];   // 32 KB: sA|sB during K loop, C-tile after
  u16* sA = smem;
  u16* sB = smem + 128 * 64;
  const int nx = gridDim.x;
  const int nwg = nx * gridDim.y;
  const int orig = blockIdx.y * nx + blockIdx.x;
  const int sw = (orig & 7) * (nwg >> 3) + (orig >> 3);
  const int m0  = (sw / nx) * 128;
  const int nn0 = (sw % nx) * 128;
  const int tid = threadIdx.x;
  const int lane = tid & 63;
  const int wv = tid >> 6;
  const int wm = wv >> 1, wn = wv & 1;
  const int rq = lane & 15, kg = lane >> 4;
  f32x4 acc[4][4];
  #pragma unroll
  for (int i = 0; i < 4; ++i)
    #pragma unroll
    for (int j = 0; j < 4; ++j) acc[i][j] = f32x4{0,0,0,0};

  for (int kt = 0; kt < 8; ++kt) {
    if (kt) __syncthreads();
    #pragma unroll
    for (int i = 0; i < 4; ++i) {
      const int c = i * 256 + tid;
      gload16(A + (size_t)(m0 + (c >> 3)) * 512 + kt * 64 + (c & 7) * 8, sA + c * 8);
    }
    #pragma unroll
    for (int i = 0; i < 4; ++i) {
      const int c = i * 256 + tid;
      gload16(Bw + (size_t)(nn0 + (c >> 3)) * 512 + kt * 64 + (c & 7) * 8, sB + c * 8);
    }
    __syncthreads();
    #pragma unroll
    for (int k0 = 0; k0 < 2; ++k0) {
      short8 af[4], bf8[4];
      #pragma unroll
      for (int mt = 0; mt < 4; ++mt)
        af[mt] = *(const short8*)(sA + (wm * 64 + mt * 16 + rq) * 64 + k0 * 32 + kg * 8);
      #pragma unroll
      for (int nt = 0; nt < 4; ++nt)
        bf8[nt] = *(const short8*)(sB + (wn * 64 + nt * 16 + rq) * 64 + k0 * 32 + kg * 8);
      #pragma unroll
      for (int mt = 0; mt < 4; ++mt)
        #pragma unroll
        for (int nt = 0; nt < 4; ++nt)
          acc[mt][nt] = mfma16(af[mt], bf8[nt], acc[mt][nt]);
    }
  }
  // ---- C tile -> LDS (swizzled), then coalesced stores ----
  __syncthreads();
  const int t = nn0 >> 9;
  const int hbase = (nn0 & 511) >> 6;
  const float sc = (t == 0) ? 0.17677669529663687f : 1.0f;
  #pragma unroll
  for (int nt = 0; nt < 4; ++nt) {
    const int col = wn * 64 + nt * 16 + rq;           // local 0..127
    const float bc = bias[nn0 + col];
    const int c = col >> 3;
    #pragma unroll
    for (int mt = 0; mt < 4; ++mt)
      #pragma unroll
      for (int r = 0; r < 4; ++r) {
        const int row = wm * 64 + mt * 16 + kg * 4 + r;  // local 0..127
        smem[row * 128 + (((c & 8) | ((c ^ row) & 7)) << 3) + (col & 7)] =
            f2bf((acc[mt][nt][r] + bc) * sc);
      }
  }
  __syncthreads();
  #pragma unroll
  for (int it = 0; it < 8; ++it) {
    const int cc = it * 256 + tid;
    const int row = cc >> 4, c = cc & 15;
    const int col = c * 8;
    const int hh = col >> 6, d = col & 63;
    const short8 v = *(const short8*)(smem + row * 128 + (((c & 8) | ((c ^ row) & 7)) << 3));
    *(short8*)(Qo + (size_t)(t * 8 + hbase + hh) * PLANE + (size_t)(m0 + row) * 64 + d) = v;
  }
}

// ---------------- barrier-free attention: one wave per (window, head), table-driven softmax ----------------
// 128-thread blocks (2 waves) -> 31 KB LDS -> 5 blocks/CU (10 waves) for latency hiding.
__global__ __launch_bounds__(128, 3) void attn3(
    const u16* __restrict__ qkv, const float* __restrict__ btab,
    u16* __restrict__ concat, int wbase)
{
  __shared__ __align__(16) u16 sP[2][3136];    // per-wave P / out buffer (49 x 64, swizzled)
  __shared__ __align__(16) u16 sVT[2][4608];   // per-wave vT: [d][tok^((d>>3)&3)<<4], stride 72

  const int tid = threadIdx.x;
  const int wv = tid >> 6, lane = tid & 63;
  const int rq = lane & 15, kg = lane >> 4;
  const int gw = blockIdx.x * 2 + wv;
  const int wl = gw >> 3, h = gw & 7;
  const int w = wbase + wl;
  const int win = w & 63, wh = win >> 3, ww = win & 7;
  const int cls = ((wh == 7) ? 1 : 0) | ((ww == 7) ? 2 : 0);
  const float* Tb = btab + (size_t)(cls * 8 + h) * 4096;
  u16* sPw = sP[wv];
  u16* sVw = sVT[wv];

  const u16* qbase = qkv + (size_t)h * PLANE + (size_t)wl * 49 * 64;
  const u16* kbase = qkv + KOFF + (size_t)h * PLANE + (size_t)wl * 49 * 64;
  const u16* vbase = qkv + VOFF + (size_t)h * PLANE + (size_t)wl * 49 * 64;

  // ---- issue v row loads early (hidden under QK^T) ----
  short8 vreg[4][2];
  #pragma unroll
  for (int t = 0; t < 4; ++t)
    #pragma unroll
    for (int h2 = 0; h2 < 2; ++h2)
      vreg[t][h2] = *(const short8*)(vbase + (size_t)(16 * t + rq) * 64 + kg * 8 + h2 * 32);

  // ---- K fragments (all), then S with per-i Q loads ----
  short8 ak[4][2];
  #pragma unroll
  for (int j = 0; j < 4; ++j) {
    const int rr = (16 * j + rq) > 48 ? 48 : (16 * j + rq);
    ak[j][0] = *(const short8*)(kbase + rr * 64 + kg * 8);
    ak[j][1] = *(const short8*)(kbase + rr * 64 + 32 + kg * 8);
  }
  f32x4 sacc[4][4];
  #pragma unroll
  for (int i = 0; i < 4; ++i)
    #pragma unroll
    for (int j = 0; j < 4; ++j) sacc[i][j] = f32x4{0,0,0,0};
  #pragma unroll
  for (int i = 0; i < 4; ++i) {
    const int rr = (16 * i + rq) > 48 ? 48 : (16 * i + rq);
    const short8 a0 = *(const short8*)(qbase + rr * 64 + kg * 8);
    const short8 a1 = *(const short8*)(qbase + rr * 64 + 32 + kg * 8);
    #pragma unroll
    for (int j = 0; j < 4; ++j) {
      sacc[i][j] = mfma16(a0, ak[j][0], sacc[i][j]);
      sacc[i][j] = mfma16(a1, ak[j][1], sacc[i][j]);
    }
  }

  // ---- write v into LDS vT (conflict-free: row ^ (kg<<4)) ----
  #pragma unroll
  for (int t = 0; t < 4; ++t) {
    const int row = 16 * t + rq;
    #pragma unroll
    for (int h2 = 0; h2 < 2; ++h2) {
      const int c0 = kg * 8 + h2 * 32;
      #pragma unroll
      for (int j = 0; j < 8; ++j)
        sVw[(c0 + j) * 72 + (row ^ (kg << 4))] = (u16)vreg[t][h2][j];
    }
  }

  // ---- table-driven softmax; P -> sPw (swizzled) ----
  #pragma unroll
  for (int i = 0; i < 4; ++i) {
    #pragma unroll
    for (int r = 0; r < 4; ++r) {
      const int n = 16 * i + kg * 4 + r;
      const float* Trow = Tb + n * 64 + rq;
      float pv[4];
      #pragma unroll
      for (int j = 0; j < 4; ++j)
        pv[j] = sacc[i][j][r] + Trow[16 * j];
      float mx = fmaxf(fmaxf(pv[0], pv[1]), fmaxf(pv[2], pv[3]));
      #pragma unroll
      for (int off = 1; off < 16; off <<= 1) mx = fmaxf(mx, __shfl_xor(mx, off));
      float sm = 0.f;
      #pragma unroll
      for (int j = 0; j < 4; ++j) { const float e = __expf(pv[j] - mx); pv[j] = e; sm += e; }
      #pragma unroll
      for (int off = 1; off < 16; off <<= 1) sm += __shfl_xor(sm, off);
      const float inv = 1.0f / sm;
      if (n < 49) {
        #pragma unroll
        for (int j = 0; j < 4; ++j) {
          const int col = 16 * j + rq;
          sPw[n * 64 + (((col >> 3) ^ (n & 7)) << 3) + (col & 7)] = f2bf(pv[j] * inv);
        }
      }
    }
  }

  // ---- PV: A = P (LDS), B = vT (LDS b128, pad toks masked) ----
  f32x4 oacc[4][4];
  #pragma unroll
  for (int i = 0; i < 4; ++i)
    #pragma unroll
    for (int j = 0; j < 4; ++j) oacc[i][j] = f32x4{0,0,0,0};
  #pragma unroll
  for (int m0v = 0; m0v < 2; ++m0v) {
    short8 av[4];
    #pragma unroll
    for (int ct = 0; ct < 4; ++ct) {
      const int col = ct * 16 + rq;
      const int s = (col >> 3) & 3;
      short8 vvv = *(const short8*)(sVw + col * 72 + ((m0v * 32 + kg * 8) ^ (s << 4)));
      if (m0v == 1) {
        if (kg == 3) {
          #pragma unroll
          for (int e = 0; e < 8; ++e) vvv[e] = 0;
        } else if (kg == 2) {
          #pragma unroll
          for (int e = 1; e < 8; ++e) vvv[e] = 0;
        }
      }
      av[ct] = vvv;
    }
    #pragma unroll
    for (int i = 0; i < 4; ++i) {
      const int rr = (16 * i + rq) > 48 ? 48 : (16 * i + rq);
      const int ch = (m0v * 4 + kg) ^ (rr & 7);
      const short8 pa = *(const short8*)(sPw + rr * 64 + ch * 8);
      #pragma unroll
      for (int ct = 0; ct < 4; ++ct)
        oacc[i][ct] = mfma16(pa, av[ct], oacc[i][ct]);
    }
  }

  // ---- repack out_h through LDS (reuse sPw), coalesced b128 store ----
  __builtin_amdgcn_s_waitcnt(0);
  #pragma unroll
  for (int i = 0; i < 4; ++i)
    #pragma unroll
    for (int ct = 0; ct < 4; ++ct)
      #pragma unroll
      for (int r = 0; r < 4; ++r) {
        const int n = 16 * i + kg * 4 + r;
        if (n < 49) {
          const int col = ct * 16 + rq;
          sPw[n * 64 + (((col >> 3) ^ (n & 7)) << 3) + (col & 7)] = f2bf(oacc[i][ct][r]);
        }
      }
  u16* crow = concat + (size_t)(wl * 49) * 512 + h * 64;
  #pragma unroll
  for (int it = 0; it < 7; ++it) {
    const int c = it * 64 + lane;
    if (c < 392) {
      const int m = c >> 3, s = c & 7;
      const short8 vvv = *(const short8*)(sPw + m * 64 + ((s ^ (m & 7)) << 3));
      *(short8*)(crow + (size_t)m * 512 + s * 8) = vvv;
    }
  }
}

// ---------------- proj GEMM + LN2 fused: BM=64, BN=256 (full row); grid 392 ----------------
__global__ __launch_bounds__(256, 3) void projln(
    const u16* __restrict__ A, const u16* __restrict__ Bw,
    const float* __restrict__ bias, const float* __restrict__ x,
    const float* __restrict__ g2, const float* __restrict__ b2,
    float* __restrict__ out, u16* __restrict__ xn2, int rowbase)
{
  __shared__ __align__(16) u16 sA[64 * 64];
  __shared__ __align__(16) u16 sB[256 * 64];
  const int m0 = blockIdx.x * 64;
  const int tid = threadIdx.x;
  const int lane = tid & 63;
  const int wv = tid >> 6;
  const int rq = lane & 15, kg = lane >> 4;
  f32x4 acc[16];
  #pragma unroll
  for (int j = 0; j < 16; ++j) acc[j] = f32x4{0,0,0,0};

  for (int kt = 0; kt < 8; ++kt) {
    if (kt) __syncthreads();
    #pragma unroll
    for (int i = 0; i < 2; ++i) {
      const int c = i * 256 + tid;
      gload16(A + (size_t)(m0 + (c >> 3)) * 512 + kt * 64 + (c & 7) * 8, sA + c * 8);
    }
    #pragma unroll
    for (int i = 0; i < 8; ++i) {
      const int c = i * 256 + tid;
      gload16(Bw + (size_t)(c >> 3) * 512 + kt * 64 + (c & 7) * 8, sB + c * 8);
    }
    __syncthreads();
    #pragma unroll
    for (int k0 = 0; k0 < 2; ++k0) {
      const short8 af = *(const short8*)(sA + (wv * 16 + rq) * 64 + k0 * 32 + kg * 8);
      #pragma unroll
      for (int nt = 0; nt < 16; ++nt) {
        const short8 bf8 = *(const short8*)(sB + (nt * 16 + rq) * 64 + k0 * 32 + kg * 8);
        acc[nt] = mfma16(af, bf8, acc[nt]);
      }
    }
  }

  float br[16], g2r[16], b2r[16];
  #pragma unroll
  for (int nt = 0; nt < 16; ++nt) {
    const int col = nt * 16 + rq;
    br[nt] = bias[col]; g2r[nt] = g2[col]; b2r[nt] = b2[col];
  }
  #pragma unroll
  for (int r = 0; r < 4; ++r) {
    const int row = m0 + wv * 16 + kg * 4 + r;
    const u32 g = (u32)(rowbase + row);
    const u32 w = g / 49u; const u32 n = g - w * 49u;
    const int b = w >> 6, win = w & 63, wh = win >> 3, ww = win & 7;
    const u32 rr = n / 7u; const u32 cc = n - rr * 7u;
    int oh = wh * 7 + (int)rr + 3; if (oh >= 56) oh -= 56;
    int ow = ww * 7 + (int)cc + 3; if (ow >= 56) ow -= 56;
    const size_t po = ((size_t)b * 3136 + oh * 56 + ow) * 256;
    float vals[16];
    float s = 0.f;
    #pragma unroll
    for (int nt = 0; nt < 16; ++nt) {
      const float v = acc[nt][r] + br[nt] + x[po + nt * 16 + rq];
      vals[nt] = v; s += v;
    }
    #pragma unroll
    for (int off = 1; off < 16; off <<= 1) s += __shfl_xor(s, off);
    const float mean = s * (1.0f / 256.0f);
    float sq = 0.f;
    #pragma unroll
    for (int nt = 0; nt < 16; ++nt) { const float d_ = vals[nt] - mean; sq += d_ * d_; }
    #pragma unroll
    for (int off = 1; off < 16; off <<= 1) sq += __shfl_xor(sq, off);
    const float rstd = rsqrtf(sq * (1.0f / 256.0f) + 1e-5f);
    #pragma unroll
    for (int nt = 0; nt < 16; ++nt) {
      const int col = nt * 16 + rq;
      out[po + col] = vals[nt];
      xn2[po + col] = f2bf((vals[nt] - mean) * rstd * g2r[nt] + b2r[nt]);
    }
  }
}

// ---------------- fused MLP (R8 v1, best known): fc1+GELU+fc2+residual, h in LDS ----------------
__global__ __launch_bounds__(256, 3) void fused_mlp(
    const u16* __restrict__ xn2, const u16* __restrict__ w1,
    const float* __restrict__ bf1, const u16* __restrict__ w2,
    const float* __restrict__ bf2v, float* __restrict__ out)
{
  __shared__ __align__(16) u16 sX[64 * 256];   // xn2 panel, chunk-swizzled
  __shared__ __align__(16) u16 sH[64 * 128];   // h tile, chunk-swizzled

  const int m0 = blockIdx.x * 64;
  const int tid = threadIdx.x;
  const int wv = tid >> 6, lane = tid & 63;
  const int rq = lane & 15, kg = lane >> 4;

  // stage xn2 panel (pre-swizzled global source, linear LDS dest)
  #pragma unroll
  for (int i = 0; i < 8; ++i) {
    const int c = i * 256 + tid;
    const int row = c >> 5, ch = c & 31;
    const int sch = (ch & 24) | ((ch ^ row) & 7);
    gload16(xn2 + (size_t)(m0 + row) * 256 + sch * 8, sX + c * 8);
  }

  f32x4 acc2[4][4];
  #pragma unroll
  for (int i = 0; i < 4; ++i)
    #pragma unroll
    for (int j = 0; j < 4; ++j) acc2[i][j] = f32x4{0,0,0,0};

  __syncthreads();

  for (int t = 0; t < 8; ++t) {
    // ---- fc1: this wave's 32 h-cols of tile t ----
    f32x4 a1[4][2];
    #pragma unroll
    for (int i = 0; i < 4; ++i)
      #pragma unroll
      for (int j = 0; j < 2; ++j) a1[i][j] = f32x4{0,0,0,0};
    #pragma unroll
    for (int ks = 0; ks < 8; ++ks) {
      short8 bfr[2];
      #pragma unroll
      for (int nt = 0; nt < 2; ++nt)
        bfr[nt] = *(const short8*)(w1 + (size_t)(t * 128 + wv * 32 + nt * 16 + rq) * 256 + ks * 32 + kg * 8);
      #pragma unroll
      for (int mt = 0; mt < 4; ++mt) {
        const int R = mt * 16 + rq;
        const int wk = ks * 4 + kg;
        const short8 af = *(const short8*)(sX + R * 256 + ((wk & 24) | ((wk ^ R) & 7)) * 8);
        #pragma unroll
        for (int nt = 0; nt < 2; ++nt)
          a1[mt][nt] = mfma16(af, bfr[nt], a1[mt][nt]);
      }
    }
    __syncthreads();   // previous tile's fc2 reads of sH complete
    // ---- bias + GELU, write h tile (swizzled) ----
    #pragma unroll
    for (int nt = 0; nt < 2; ++nt) {
      const int col = wv * 32 + nt * 16 + rq;
      const float bb = bf1[t * 128 + col];
      const int ch = col >> 3;
      #pragma unroll
      for (int mt = 0; mt < 4; ++mt)
        #pragma unroll
        for (int r = 0; r < 4; ++r) {
          const int row = mt * 16 + kg * 4 + r;
          sH[row * 128 + ((ch & 8) | ((ch ^ row) & 7)) * 8 + (col & 7)] =
              f2bf(gelu_t(a1[mt][nt][r] + bb));
        }
    }
    __syncthreads();   // h tile visible
    // ---- fc2 partial: all 64 rows x this wave's 64 cols, k = t*128..+128 ----
    #pragma unroll
    for (int ks = 0; ks < 4; ++ks) {
      short8 bfr2[4];
      #pragma unroll
      for (int nt = 0; nt < 4; ++nt)
        bfr2[nt] = *(const short8*)(w2 + (size_t)(wv * 64 + nt * 16 + rq) * 1024 + t * 128 + ks * 32 + kg * 8);
      #pragma unroll
      for (int mt = 0; mt < 4; ++mt) {
        const int R = mt * 16 + rq;
        const int wk = ks * 4 + kg;
        const short8 af = *(const short8*)(sH + R * 128 + ((wk & 8) | ((wk ^ R) & 7)) * 8);
        #pragma unroll
        for (int nt = 0; nt < 4; ++nt)
          acc2[mt][nt] = mfma16(af, bfr2[nt], acc2[mt][nt]);
      }
    }
  }

  // ---- epilogue: + b_fc2 + residual RMW ----
  #pragma unroll
  for (int nt = 0; nt < 4; ++nt) {
    const int col = wv * 64 + nt * 16 + rq;
    const float bb = bf2v[col];
    #pragma unroll
    for (int mt = 0; mt < 4; ++mt)
      #pragma unroll
      for (int r = 0; r < 4; ++r) {
        float* p = out + (size_t)(m0 + mt * 16 + kg * 4 + r) * 256 + col;
        *p = acc2[mt][nt][r] + bb + *p;
      }
  }
}

extern "C" void kernel_launch(void* const* d_in, const int* in_sizes, int n_in,
                              void* d_out, int out_size, void* d_ws, size_t ws_size,
                              hipStream_t stream) {
  const float* x      = (const float*)d_in[0];
  const float* y      = (const float*)d_in[1];
  const float* g1     = (const float*)d_in[2];
  const float* b1     = (const float*)d_in[3];
  const float* rpb    = (const float*)d_in[4];
  const float* w_qkv  = (const float*)d_in[5];
  const float* b_qkv  = (const float*)d_in[6];
  const float* w_proj = (const float*)d_in[7];
  const float* b_proj = (const float*)d_in[8];
  const float* g2     = (const float*)d_in[9];
  const float* b2     = (const float*)d_in[10];
  const float* w_fc1  = (const float*)d_in[11];
  const float* b_fc1  = (const float*)d_in[12];
  const float* w_fc2  = (const float*)d_in[13];
  const float* b_fc2  = (const float*)d_in[14];
  float* out = (float*)d_out;

  u16* wsp = (u16*)d_ws;
  u16* wqkv_bf  = wsp;                       //  786432
  u16* wproj_bf = wsp + 786432;              //  131072
  u16* wfc1_bf  = wsp + 917504;              //  262144
  u16* wfc2_bf  = wsp + 1179648;             //  262144
  float* btab   = (float*)(wsp + 1441792);   //  131072 f32
  u16* xn2      = wsp + 1703936;             //  25690112
  u16* XYc      = wsp + 27394048;            //  12845056 (25088 x 512)
  u16* qkvc     = wsp + 40239104;            //  24 planes x 25088 x 64

  convall<<<1408, 256, 0, stream>>>(w_qkv, w_proj, w_fc1, w_fc2,
                                    wqkv_bf, wproj_bf, wfc1_bf, wfc2_bf);
  btab_build<<<32, 256, 0, stream>>>(rpb, btab);

  for (int c = 0; c < 4; ++c) {
    ln_gather<<<6272, 256, 0, stream>>>(x, y, g1, b1, XYc, c * CHUNK_ROWS);
    qkv_gemm<<<dim3(12, 196), 256, 0, stream>>>(XYc, wqkv_bf, b_qkv, qkvc);
    attn3<<<2048, 128, 0, stream>>>(qkvc, btab, XYc, c * 512);
    projln<<<392, 256, 0, stream>>>(XYc, wproj_bf, b_proj, x, g2, b2, out, xn2, c * CHUNK_ROWS);
  }

  fused_mlp<<<1568, 256, 0, stream>>>(xn2, wfc1_bf, b_fc1, wfc2_bf, b_fc2, out);
}

// Round 14
// 806.530 us; speedup vs baseline: 1.1261x; 1.0444x over previous
//
#include <hip/hip_runtime.h>
#include <hip/hip_bf16.h>

#define DEVI __device__ __forceinline__

typedef __attribute__((ext_vector_type(8))) short short8;
typedef __attribute__((ext_vector_type(4))) float f32x4;
typedef unsigned int u32;
typedef unsigned short u16;

typedef __attribute__((address_space(1))) const u32 gu32_t;
typedef __attribute__((address_space(3))) u32 lu32_t;

DEVI u16 f2bf(float f) {
  u32 u = __builtin_bit_cast(u32, f);
  u32 r = (u + 0x7fffu + ((u >> 16) & 1u)) >> 16;
  return (u16)r;
}

DEVI f32x4 mfma16(short8 a, short8 b, f32x4 c) {
  return __builtin_amdgcn_mfma_f32_16x16x32_bf16(a, b, c, 0, 0, 0);
}

DEVI void gload16(const void* g, void* l) {
  __builtin_amdgcn_global_load_lds((gu32_t*)g, (lu32_t*)l, 16, 0, 0);
}

DEVI float gelu_t(float v) {
  const float u = v * (0.7978845608f + 0.0356774081f * v * v);
  const float t = 1.0f - 2.0f / (__expf(2.0f * u) + 1.0f);
  return 0.5f * v * (1.0f + t);
}

#define CHUNK_ROWS 25088   // 512 windows * 49 tokens
#define PLANE ((size_t)CHUNK_ROWS * 64)
#define KOFF  ((size_t)8 * PLANE)          // k planes base
#define VOFF  ((size_t)16 * PLANE)         // v planes base (linear)

// ---------------- qkv/proj weights f32 -> bf16 (row-major kept; staged via gload_lds) ----------------
__global__ __launch_bounds__(256) void convall(
    const float* __restrict__ wq, const float* __restrict__ wp,
    u16* __restrict__ dq, u16* __restrict__ dp)
{
  const int i = blockIdx.x * 256 + threadIdx.x;   // float4 index, 0..229375
  const float* s; u16* d; int off;
  if (i < 196608) { s = wq; d = dq; off = i; }
  else            { s = wp; d = dp; off = i - 196608; }
  const float4 v = ((const float4*)s)[off];
  ushort4 o;
  o.x = f2bf(v.x); o.y = f2bf(v.y); o.z = f2bf(v.z); o.w = f2bf(v.w);
  ((ushort4*)d)[off] = o;
}

// ---------------- MLP weights: repack into fragment order ----------------
// w1p: [(t*8+ks)*4+kg][colL 0..127][e 0..7], col = t*128+colL, k = ks*32+kg*8+e
// w2p: [(t*4+ks)*4+kg][outcol 0..255][e 0..7], k = t*128+ks*32+kg*8+e
// -> a wave's fragment load is lane-linear (8 fully-used 128B lines / instr).
__global__ __launch_bounds__(256) void repack_mlp(
    const float* __restrict__ w1, const float* __restrict__ w2,
    u16* __restrict__ w1p, u16* __restrict__ w2p)
{
  const int g = blockIdx.x * 256 + threadIdx.x;   // dest short8 index
  if (g < 32768) {
    const int e0 = g * 8;
    const int chunk = e0 >> 10;
    const int colL = (e0 >> 3) & 127;
    const int kg = chunk & 3, tks = chunk >> 2;
    const int ks = tks & 7, t = tks >> 3;
    const int col = t * 128 + colL;
    const int kb = ks * 32 + kg * 8;
    short8 v;
    #pragma unroll
    for (int e = 0; e < 8; ++e) v[e] = (short)f2bf(w1[col * 256 + kb + e]);
    *(short8*)(w1p + e0) = v;
  } else {
    const int e0 = (g - 32768) * 8;
    const int chunk = e0 >> 11;
    const int outcol = (e0 >> 3) & 255;
    const int kg = chunk & 3, tks = chunk >> 2;
    const int ks = tks & 3, t = tks >> 2;
    const int kb = t * 128 + ks * 32 + kg * 8;
    short8 v;
    #pragma unroll
    for (int e = 0; e < 8; ++e) v[e] = (short)f2bf(w2[outcol * 1024 + kb + e]);
    *(short8*)(w2p + e0) = v;
  }
}

// ---------------- fused bias+mask+pad table: [4 cls][8 h][64 n][64 m] f32 ----------------
__global__ __launch_bounds__(256) void btab_build(const float* __restrict__ rpb, float* __restrict__ btab) {
  const int cls = blockIdx.x >> 3, h = blockIdx.x & 7;
  float* dst = btab + (size_t)(cls * 8 + h) * 4096;
  for (int e = threadIdx.x; e < 4096; e += 256) {
    const int n = e >> 6, m = e & 63;
    float v;
    if (m >= 49) {
      v = -1e30f;
    } else if (n >= 49) {
      v = 0.f;
    } else {
      const int r1 = n / 7, c1 = n - r1 * 7;
      const int r2 = m / 7, c2 = m - r2 * 7;
      const int rel = (r1 - r2 + 6) * 13 + (c1 - c2 + 6);
      v = rpb[rel * 8 + h];
      const int reg1 = ((cls & 1) ? (r1 < 4 ? 1 : 2) : 0) * 3 + ((cls & 2) ? (c1 < 4 ? 1 : 2) : 0);
      const int reg2 = ((cls & 1) ? (r2 < 4 ? 1 : 2) : 0) * 3 + ((cls & 2) ? (c2 < 4 ? 1 : 2) : 0);
      if (reg1 != reg2) v -= 100.f;
    }
    dst[e] = v;
  }
}

// ---------------- LN1 + shift + window gather -> XY bf16 [CHUNK_ROWS][512] ----------------
__global__ __launch_bounds__(256) void ln_gather(
    const float* __restrict__ x, const float* __restrict__ y,
    const float* __restrict__ g1, const float* __restrict__ b1,
    u16* __restrict__ XY, int rowbase)
{
  const int wv = threadIdx.x >> 6, lane = threadIdx.x & 63;
  const int rl = blockIdx.x * 4 + wv;
  const int row = rowbase + rl;
  const int w = row / 49, n = row - w * 49;
  const int b = w >> 6, win = w & 63, wh = win >> 3, ww = win & 7;
  const int r = n / 7, c = n - r * 7;
  int oh = wh * 7 + r + 3; if (oh >= 56) oh -= 56;
  int ow = ww * 7 + c + 3; if (ow >= 56) ow -= 56;
  const size_t po = ((size_t)b * 3136 + oh * 56 + ow) * 256;
  const float4 g1v = ((const float4*)g1)[lane];
  const float4 b1v = ((const float4*)b1)[lane];
  u16* orow = XY + (size_t)rl * 512;
  #pragma unroll
  for (int mod = 0; mod < 2; ++mod) {
    const float* src = (mod ? y : x) + po;
    const float4 v = ((const float4*)src)[lane];
    float s = v.x + v.y + v.z + v.w;
    #pragma unroll
    for (int off = 1; off < 64; off <<= 1) s += __shfl_xor(s, off);
    const float mean = s * (1.0f / 256.0f);
    const float d0 = v.x - mean, d1 = v.y - mean, d2 = v.z - mean, d3 = v.w - mean;
    float sq = d0 * d0 + d1 * d1 + d2 * d2 + d3 * d3;
    #pragma unroll
    for (int off = 1; off < 64; off <<= 1) sq += __shfl_xor(sq, off);
    const float rstd = rsqrtf(sq * (1.0f / 256.0f) + 1e-5f);
    ushort4 o;
    o.x = f2bf(d0 * rstd * g1v.x + b1v.x);
    o.y = f2bf(d1 * rstd * g1v.y + b1v.y);
    o.z = f2bf(d2 * rstd * g1v.z + b1v.z);
    o.w = f2bf(d3 * rstd * g1v.w + b1v.w);
    *(ushort4*)(orow + mod * 256 + lane * 4) = o;
  }
}

// ---------------- QKV GEMM (128x128, XCD-swizzled): M=25088, N=1536, K=512 ----------------
__global__ __launch_bounds__(256) void qkv_gemm(
    const u16* __restrict__ A, const u16* __restrict__ Bw,
    const float* __restrict__ bias, u16* __restrict__ Qo)
{
  __shared__ __align__(16) u16 smem[128 * 128];
  u16* sA = smem;
  u16* sB = smem + 128 * 64;
  const int nx = gridDim.x;
  const int nwg = nx * gridDim.y;
  const int orig = blockIdx.y * nx + blockIdx.x;
  const int sw = (orig & 7) * (nwg >> 3) + (orig >> 3);
  const int m0  = (sw / nx) * 128;
  const int nn0 = (sw % nx) * 128;
  const int tid = threadIdx.x;
  const int lane = tid & 63;
  const int wv = tid >> 6;
  const int wm = wv >> 1, wn = wv & 1;
  const int rq = lane & 15, kg = lane >> 4;
  f32x4 acc[4][4];
  #pragma unroll
  for (int i = 0; i < 4; ++i)
    #pragma unroll
    for (int j = 0; j < 4; ++j) acc[i][j] = f32x4{0,0,0,0};

  for (int kt = 0; kt < 8; ++kt) {
    if (kt) __syncthreads();
    #pragma unroll
    for (int i = 0; i < 4; ++i) {
      const int c = i * 256 + tid;
      gload16(A + (size_t)(m0 + (c >> 3)) * 512 + kt * 64 + (c & 7) * 8, sA + c * 8);
    }
    #pragma unroll
    for (int i = 0; i < 4; ++i) {
      const int c = i * 256 + tid;
      gload16(Bw + (size_t)(nn0 + (c >> 3)) * 512 + kt * 64 + (c & 7) * 8, sB + c * 8);
    }
    __syncthreads();
    #pragma unroll
    for (int k0 = 0; k0 < 2; ++k0) {
      short8 af[4], bf8[4];
      #pragma unroll
      for (int mt = 0; mt < 4; ++mt)
        af[mt] = *(const short8*)(sA + (wm * 64 + mt * 16 + rq) * 64 + k0 * 32 + kg * 8);
      #pragma unroll
      for (int nt = 0; nt < 4; ++nt)
        bf8[nt] = *(const short8*)(sB + (wn * 64 + nt * 16 + rq) * 64 + k0 * 32 + kg * 8);
      #pragma unroll
      for (int mt = 0; mt < 4; ++mt)
        #pragma unroll
        for (int nt = 0; nt < 4; ++nt)
          acc[mt][nt] = mfma16(af[mt], bf8[nt], acc[mt][nt]);
    }
  }
  __syncthreads();
  const int t = nn0 >> 9;
  const int hbase = (nn0 & 511) >> 6;
  const float sc = (t == 0) ? 0.17677669529663687f : 1.0f;
  #pragma unroll
  for (int nt = 0; nt < 4; ++nt) {
    const int col = wn * 64 + nt * 16 + rq;
    const float bc = bias[nn0 + col];
    const int c = col >> 3;
    #pragma unroll
    for (int mt = 0; mt < 4; ++mt)
      #pragma unroll
      for (int r = 0; r < 4; ++r) {
        const int row = wm * 64 + mt * 16 + kg * 4 + r;
        smem[row * 128 + (((c & 8) | ((c ^ row) & 7)) << 3) + (col & 7)] =
            f2bf((acc[mt][nt][r] + bc) * sc);
      }
  }
  __syncthreads();
  #pragma unroll
  for (int it = 0; it < 8; ++it) {
    const int cc = it * 256 + tid;
    const int row = cc >> 4, c = cc & 15;
    const int col = c * 8;
    const int hh = col >> 6, d = col & 63;
    const short8 v = *(const short8*)(smem + row * 128 + (((c & 8) | ((c ^ row) & 7)) << 3));
    *(short8*)(Qo + (size_t)(t * 8 + hbase + hh) * PLANE + (size_t)(m0 + row) * 64 + d) = v;
  }
}

// ---------------- barrier-free attention (2-wave blocks, table-driven softmax) ----------------
__global__ __launch_bounds__(128, 3) void attn3(
    const u16* __restrict__ qkv, const float* __restrict__ btab,
    u16* __restrict__ concat, int wbase)
{
  __shared__ __align__(16) u16 sP[2][3136];
  __shared__ __align__(16) u16 sVT[2][4608];

  const int tid = threadIdx.x;
  const int wv = tid >> 6, lane = tid & 63;
  const int rq = lane & 15, kg = lane >> 4;
  const int gw = blockIdx.x * 2 + wv;
  const int wl = gw >> 3, h = gw & 7;
  const int w = wbase + wl;
  const int win = w & 63, wh = win >> 3, ww = win & 7;
  const int cls = ((wh == 7) ? 1 : 0) | ((ww == 7) ? 2 : 0);
  const float* Tb = btab + (size_t)(cls * 8 + h) * 4096;
  u16* sPw = sP[wv];
  u16* sVw = sVT[wv];

  const u16* qbase = qkv + (size_t)h * PLANE + (size_t)wl * 49 * 64;
  const u16* kbase = qkv + KOFF + (size_t)h * PLANE + (size_t)wl * 49 * 64;
  const u16* vbase = qkv + VOFF + (size_t)h * PLANE + (size_t)wl * 49 * 64;

  short8 vreg[4][2];
  #pragma unroll
  for (int t = 0; t < 4; ++t)
    #pragma unroll
    for (int h2 = 0; h2 < 2; ++h2)
      vreg[t][h2] = *(const short8*)(vbase + (size_t)(16 * t + rq) * 64 + kg * 8 + h2 * 32);

  short8 ak[4][2];
  #pragma unroll
  for (int j = 0; j < 4; ++j) {
    const int rr = (16 * j + rq) > 48 ? 48 : (16 * j + rq);
    ak[j][0] = *(const short8*)(kbase + rr * 64 + kg * 8);
    ak[j][1] = *(const short8*)(kbase + rr * 64 + 32 + kg * 8);
  }
  f32x4 sacc[4][4];
  #pragma unroll
  for (int i = 0; i < 4; ++i)
    #pragma unroll
    for (int j = 0; j < 4; ++j) sacc[i][j] = f32x4{0,0,0,0};
  #pragma unroll
  for (int i = 0; i < 4; ++i) {
    const int rr = (16 * i + rq) > 48 ? 48 : (16 * i + rq);
    const short8 a0 = *(const short8*)(qbase + rr * 64 + kg * 8);
    const short8 a1 = *(const short8*)(qbase + rr * 64 + 32 + kg * 8);
    #pragma unroll
    for (int j = 0; j < 4; ++j) {
      sacc[i][j] = mfma16(a0, ak[j][0], sacc[i][j]);
      sacc[i][j] = mfma16(a1, ak[j][1], sacc[i][j]);
    }
  }

  #pragma unroll
  for (int t = 0; t < 4; ++t) {
    const int row = 16 * t + rq;
    #pragma unroll
    for (int h2 = 0; h2 < 2; ++h2) {
      const int c0 = kg * 8 + h2 * 32;
      #pragma unroll
      for (int j = 0; j < 8; ++j)
        sVw[(c0 + j) * 72 + (row ^ (kg << 4))] = (u16)vreg[t][h2][j];
    }
  }

  #pragma unroll
  for (int i = 0; i < 4; ++i) {
    #pragma unroll
    for (int r = 0; r < 4; ++r) {
      const int n = 16 * i + kg * 4 + r;
      const float* Trow = Tb + n * 64 + rq;
      float pv[4];
      #pragma unroll
      for (int j = 0; j < 4; ++j)
        pv[j] = sacc[i][j][r] + Trow[16 * j];
      float mx = fmaxf(fmaxf(pv[0], pv[1]), fmaxf(pv[2], pv[3]));
      #pragma unroll
      for (int off = 1; off < 16; off <<= 1) mx = fmaxf(mx, __shfl_xor(mx, off));
      float sm = 0.f;
      #pragma unroll
      for (int j = 0; j < 4; ++j) { const float e = __expf(pv[j] - mx); pv[j] = e; sm += e; }
      #pragma unroll
      for (int off = 1; off < 16; off <<= 1) sm += __shfl_xor(sm, off);
      const float inv = 1.0f / sm;
      if (n < 49) {
        #pragma unroll
        for (int j = 0; j < 4; ++j) {
          const int col = 16 * j + rq;
          sPw[n * 64 + (((col >> 3) ^ (n & 7)) << 3) + (col & 7)] = f2bf(pv[j] * inv);
        }
      }
    }
  }

  f32x4 oacc[4][4];
  #pragma unroll
  for (int i = 0; i < 4; ++i)
    #pragma unroll
    for (int j = 0; j < 4; ++j) oacc[i][j] = f32x4{0,0,0,0};
  #pragma unroll
  for (int m0v = 0; m0v < 2; ++m0v) {
    short8 av[4];
    #pragma unroll
    for (int ct = 0; ct < 4; ++ct) {
      const int col = ct * 16 + rq;
      const int s = (col >> 3) & 3;
      short8 vvv = *(const short8*)(sVw + col * 72 + ((m0v * 32 + kg * 8) ^ (s << 4)));
      if (m0v == 1) {
        if (kg == 3) {
          #pragma unroll
          for (int e = 0; e < 8; ++e) vvv[e] = 0;
        } else if (kg == 2) {
          #pragma unroll
          for (int e = 1; e < 8; ++e) vvv[e] = 0;
        }
      }
      av[ct] = vvv;
    }
    #pragma unroll
    for (int i = 0; i < 4; ++i) {
      const int rr = (16 * i + rq) > 48 ? 48 : (16 * i + rq);
      const int ch = (m0v * 4 + kg) ^ (rr & 7);
      const short8 pa = *(const short8*)(sPw + rr * 64 + ch * 8);
      #pragma unroll
      for (int ct = 0; ct < 4; ++ct)
        oacc[i][ct] = mfma16(pa, av[ct], oacc[i][ct]);
    }
  }

  __builtin_amdgcn_s_waitcnt(0);
  #pragma unroll
  for (int i = 0; i < 4; ++i)
    #pragma unroll
    for (int ct = 0; ct < 4; ++ct)
      #pragma unroll
      for (int r = 0; r < 4; ++r) {
        const int n = 16 * i + kg * 4 + r;
        if (n < 49) {
          const int col = ct * 16 + rq;
          sPw[n * 64 + (((col >> 3) ^ (n & 7)) << 3) + (col & 7)] = f2bf(oacc[i][ct][r]);
        }
      }
  u16* crow = concat + (size_t)(wl * 49) * 512 + h * 64;
  #pragma unroll
  for (int it = 0; it < 7; ++it) {
    const int c = it * 64 + lane;
    if (c < 392) {
      const int m = c >> 3, s = c & 7;
      const short8 vvv = *(const short8*)(sPw + m * 64 + ((s ^ (m & 7)) << 3));
      *(short8*)(crow + (size_t)m * 512 + s * 8) = vvv;
    }
  }
}

// ---------------- proj GEMM + LN2 fused: BM=64, BN=256 (full row); grid 392 ----------------
__global__ __launch_bounds__(256, 3) void projln(
    const u16* __restrict__ A, const u16* __restrict__ Bw,
    const float* __restrict__ bias, const float* __restrict__ x,
    const float* __restrict__ g2, const float* __restrict__ b2,
    float* __restrict__ out, u16* __restrict__ xn2, int rowbase)
{
  __shared__ __align__(16) u16 sA[64 * 64];
  __shared__ __align__(16) u16 sB[256 * 64];
  const int m0 = blockIdx.x * 64;
  const int tid = threadIdx.x;
  const int lane = tid & 63;
  const int wv = tid >> 6;
  const int rq = lane & 15, kg = lane >> 4;
  f32x4 acc[16];
  #pragma unroll
  for (int j = 0; j < 16; ++j) acc[j] = f32x4{0,0,0,0};

  for (int kt = 0; kt < 8; ++kt) {
    if (kt) __syncthreads();
    #pragma unroll
    for (int i = 0; i < 2; ++i) {
      const int c = i * 256 + tid;
      gload16(A + (size_t)(m0 + (c >> 3)) * 512 + kt * 64 + (c & 7) * 8, sA + c * 8);
    }
    #pragma unroll
    for (int i = 0; i < 8; ++i) {
      const int c = i * 256 + tid;
      gload16(Bw + (size_t)(c >> 3) * 512 + kt * 64 + (c & 7) * 8, sB + c * 8);
    }
    __syncthreads();
    #pragma unroll
    for (int k0 = 0; k0 < 2; ++k0) {
      const short8 af = *(const short8*)(sA + (wv * 16 + rq) * 64 + k0 * 32 + kg * 8);
      #pragma unroll
      for (int nt = 0; nt < 16; ++nt) {
        const short8 bf8 = *(const short8*)(sB + (nt * 16 + rq) * 64 + k0 * 32 + kg * 8);
        acc[nt] = mfma16(af, bf8, acc[nt]);
      }
    }
  }

  float br[16], g2r[16], b2r[16];
  #pragma unroll
  for (int nt = 0; nt < 16; ++nt) {
    const int col = nt * 16 + rq;
    br[nt] = bias[col]; g2r[nt] = g2[col]; b2r[nt] = b2[col];
  }
  #pragma unroll
  for (int r = 0; r < 4; ++r) {
    const int row = m0 + wv * 16 + kg * 4 + r;
    const u32 g = (u32)(rowbase + row);
    const u32 w = g / 49u; const u32 n = g - w * 49u;
    const int b = w >> 6, win = w & 63, wh = win >> 3, ww = win & 7;
    const u32 rr = n / 7u; const u32 cc = n - rr * 7u;
    int oh = wh * 7 + (int)rr + 3; if (oh >= 56) oh -= 56;
    int ow = ww * 7 + (int)cc + 3; if (ow >= 56) ow -= 56;
    const size_t po = ((size_t)b * 3136 + oh * 56 + ow) * 256;
    float vals[16];
    float s = 0.f;
    #pragma unroll
    for (int nt = 0; nt < 16; ++nt) {
      const float v = acc[nt][r] + br[nt] + x[po + nt * 16 + rq];
      vals[nt] = v; s += v;
    }
    #pragma unroll
    for (int off = 1; off < 16; off <<= 1) s += __shfl_xor(s, off);
    const float mean = s * (1.0f / 256.0f);
    float sq = 0.f;
    #pragma unroll
    for (int nt = 0; nt < 16; ++nt) { const float d_ = vals[nt] - mean; sq += d_ * d_; }
    #pragma unroll
    for (int off = 1; off < 16; off <<= 1) sq += __shfl_xor(sq, off);
    const float rstd = rsqrtf(sq * (1.0f / 256.0f) + 1e-5f);
    #pragma unroll
    for (int nt = 0; nt < 16; ++nt) {
      const int col = nt * 16 + rq;
      out[po + col] = vals[nt];
      xn2[po + col] = f2bf((vals[nt] - mean) * rstd * g2r[nt] + b2r[nt]);
    }
  }
}

// ---------------- fused MLP (R8-v1 structure + fragment-order weight loads) ----------------
__global__ __launch_bounds__(256, 3) void fused_mlp(
    const u16* __restrict__ xn2, const u16* __restrict__ w1p,
    const float* __restrict__ bf1, const u16* __restrict__ w2p,
    const float* __restrict__ bf2v, float* __restrict__ out)
{
  __shared__ __align__(16) u16 sX[64 * 256];   // xn2 panel, chunk-swizzled
  __shared__ __align__(16) u16 sH[64 * 128];   // h tile, chunk-swizzled

  const int m0 = blockIdx.x * 64;
  const int tid = threadIdx.x;
  const int wv = tid >> 6, lane = tid & 63;
  const int rq = lane & 15, kg = lane >> 4;

  #pragma unroll
  for (int i = 0; i < 8; ++i) {
    const int c = i * 256 + tid;
    const int row = c >> 5, ch = c & 31;
    const int sch = (ch & 24) | ((ch ^ row) & 7);
    gload16(xn2 + (size_t)(m0 + row) * 256 + sch * 8, sX + c * 8);
  }

  f32x4 acc2[4][4];
  #pragma unroll
  for (int i = 0; i < 4; ++i)
    #pragma unroll
    for (int j = 0; j < 4; ++j) acc2[i][j] = f32x4{0,0,0,0};

  __syncthreads();

  for (int t = 0; t < 8; ++t) {
    // ---- fc1: fragment-order weight loads (lane-linear, 8 full lines/instr) ----
    f32x4 a1[4][2];
    #pragma unroll
    for (int i = 0; i < 4; ++i)
      #pragma unroll
      for (int j = 0; j < 2; ++j) a1[i][j] = f32x4{0,0,0,0};
    #pragma unroll
    for (int ks = 0; ks < 8; ++ks) {
      const u16* wb = w1p + ((size_t)((t * 8 + ks) * 4 + kg)) * 1024;
      short8 bfr[2];
      #pragma unroll
      for (int nt = 0; nt < 2; ++nt)
        bfr[nt] = *(const short8*)(wb + (wv * 32 + nt * 16 + rq) * 8);
      #pragma unroll
      for (int mt = 0; mt < 4; ++mt) {
        const int R = mt * 16 + rq;
        const int wk = ks * 4 + kg;
        const short8 af = *(const short8*)(sX + R * 256 + ((wk & 24) | ((wk ^ R) & 7)) * 8);
        #pragma unroll
        for (int nt = 0; nt < 2; ++nt)
          a1[mt][nt] = mfma16(af, bfr[nt], a1[mt][nt]);
      }
    }
    __syncthreads();   // previous tile's fc2 reads of sH complete
    // ---- bias + GELU, write h tile (swizzled) ----
    #pragma unroll
    for (int nt = 0; nt < 2; ++nt) {
      const int col = wv * 32 + nt * 16 + rq;
      const float bb = bf1[t * 128 + col];
      const int ch = col >> 3;
      #pragma unroll
      for (int mt = 0; mt < 4; ++mt)
        #pragma unroll
        for (int r = 0; r < 4; ++r) {
          const int row = mt * 16 + kg * 4 + r;
          sH[row * 128 + ((ch & 8) | ((ch ^ row) & 7)) * 8 + (col & 7)] =
              f2bf(gelu_t(a1[mt][nt][r] + bb));
        }
    }
    __syncthreads();   // h tile visible
    // ---- fc2: fragment-order weight loads ----
    #pragma unroll
    for (int ks = 0; ks < 4; ++ks) {
      const u16* wb = w2p + ((size_t)((t * 4 + ks) * 4 + kg)) * 2048;
      short8 bfr2[4];
      #pragma unroll
      for (int nt = 0; nt < 4; ++nt)
        bfr2[nt] = *(const short8*)(wb + (wv * 64 + nt * 16 + rq) * 8);
      #pragma unroll
      for (int mt = 0; mt < 4; ++mt) {
        const int R = mt * 16 + rq;
        const int wk = ks * 4 + kg;
        const short8 af = *(const short8*)(sH + R * 128 + ((wk & 8) | ((wk ^ R) & 7)) * 8);
        #pragma unroll
        for (int nt = 0; nt < 4; ++nt)
          acc2[mt][nt] = mfma16(af, bfr2[nt], acc2[mt][nt]);
      }
    }
  }

  // ---- epilogue: + b_fc2 + residual RMW ----
  #pragma unroll
  for (int nt = 0; nt < 4; ++nt) {
    const int col = wv * 64 + nt * 16 + rq;
    const float bb = bf2v[col];
    #pragma unroll
    for (int mt = 0; mt < 4; ++mt)
      #pragma unroll
      for (int r = 0; r < 4; ++r) {
        float* p = out + (size_t)(m0 + mt * 16 + kg * 4 + r) * 256 + col;
        *p = acc2[mt][nt][r] + bb + *p;
      }
  }
}

extern "C" void kernel_launch(void* const* d_in, const int* in_sizes, int n_in,
                              void* d_out, int out_size, void* d_ws, size_t ws_size,
                              hipStream_t stream) {
  const float* x      = (const float*)d_in[0];
  const float* y      = (const float*)d_in[1];
  const float* g1     = (const float*)d_in[2];
  const float* b1     = (const float*)d_in[3];
  const float* rpb    = (const float*)d_in[4];
  const float* w_qkv  = (const float*)d_in[5];
  const float* b_qkv  = (const float*)d_in[6];
  const float* w_proj = (const float*)d_in[7];
  const float* b_proj = (const float*)d_in[8];
  const float* g2     = (const float*)d_in[9];
  const float* b2     = (const float*)d_in[10];
  const float* w_fc1  = (const float*)d_in[11];
  const float* b_fc1  = (const float*)d_in[12];
  const float* w_fc2  = (const float*)d_in[13];
  const float* b_fc2  = (const float*)d_in[14];
  float* out = (float*)d_out;

  u16* wsp = (u16*)d_ws;
  u16* wqkv_bf  = wsp;                       //  786432
  u16* wproj_bf = wsp + 786432;              //  131072
  u16* w1p      = wsp + 917504;              //  262144 (fragment-order)
  u16* w2p      = wsp + 1179648;             //  262144 (fragment-order)
  float* btab   = (float*)(wsp + 1441792);   //  131072 f32
  u16* xn2      = wsp + 1703936;             //  25690112
  u16* XYc      = wsp + 27394048;            //  12845056 (25088 x 512)
  u16* qkvc     = wsp + 40239104;            //  24 planes x 25088 x 64

  convall<<<896, 256, 0, stream>>>(w_qkv, w_proj, wqkv_bf, wproj_bf);
  repack_mlp<<<256, 256, 0, stream>>>(w_fc1, w_fc2, w1p, w2p);
  btab_build<<<32, 256, 0, stream>>>(rpb, btab);

  for (int c = 0; c < 4; ++c) {
    ln_gather<<<6272, 256, 0, stream>>>(x, y, g1, b1, XYc, c * CHUNK_ROWS);
    qkv_gemm<<<dim3(12, 196), 256, 0, stream>>>(XYc, wqkv_bf, b_qkv, qkvc);
    attn3<<<2048, 128, 0, stream>>>(qkvc, btab, XYc, c * 512);
    projln<<<392, 256, 0, stream>>>(XYc, wproj_bf, b_proj, x, g2, b2, out, xn2, c * CHUNK_ROWS);
  }

  fused_mlp<<<1568, 256, 0, stream>>>(xn2, w1p, b_fc1, w2p, b_fc2, out);
}

// Round 15
// 792.840 us; speedup vs baseline: 1.1456x; 1.0173x over previous
//
#include <hip/hip_runtime.h>
#include <hip/hip_bf16.h>

#define DEVI __device__ __forceinline__

typedef __attribute__((ext_vector_type(8))) short short8;
typedef __attribute__((ext_vector_type(4))) float f32x4;
typedef unsigned int u32;
typedef unsigned short u16;

typedef __attribute__((address_space(1))) const u32 gu32_t;
typedef __attribute__((address_space(3))) u32 lu32_t;

DEVI u16 f2bf(float f) {
  u32 u = __builtin_bit_cast(u32, f);
  u32 r = (u + 0x7fffu + ((u >> 16) & 1u)) >> 16;
  return (u16)r;
}

DEVI f32x4 mfma16(short8 a, short8 b, f32x4 c) {
  return __builtin_amdgcn_mfma_f32_16x16x32_bf16(a, b, c, 0, 0, 0);
}

DEVI void gload16(const void* g, void* l) {
  __builtin_amdgcn_global_load_lds((gu32_t*)g, (lu32_t*)l, 16, 0, 0);
}

DEVI float gelu_s(float v) {        // x * sigmoid(1.702x), |err| <= ~0.02
  return v / (1.0f + __expf(-1.702f * v));
}

#define CHUNK_ROWS 25088   // 512 windows * 49 tokens
#define PLANE ((size_t)CHUNK_ROWS * 64)
#define KOFF  ((size_t)8 * PLANE)          // k planes base
#define VOFF  ((size_t)16 * PLANE)         // v planes base
// per-(h,window) fragment layout: [c8=d>>3][tok 0..48][e 0..7], 3136 u16/window

// ---------------- qkv/proj weights f32 -> bf16 ----------------
__global__ __launch_bounds__(256) void convall(
    const float* __restrict__ wq, const float* __restrict__ wp,
    u16* __restrict__ dq, u16* __restrict__ dp)
{
  const int i = blockIdx.x * 256 + threadIdx.x;
  const float* s; u16* d; int off;
  if (i < 196608) { s = wq; d = dq; off = i; }
  else            { s = wp; d = dp; off = i - 196608; }
  const float4 v = ((const float4*)s)[off];
  ushort4 o;
  o.x = f2bf(v.x); o.y = f2bf(v.y); o.z = f2bf(v.z); o.w = f2bf(v.w);
  ((ushort4*)d)[off] = o;
}

// ---------------- MLP weights: repack into fragment order ----------------
__global__ __launch_bounds__(256) void repack_mlp(
    const float* __restrict__ w1, const float* __restrict__ w2,
    u16* __restrict__ w1p, u16* __restrict__ w2p)
{
  const int g = blockIdx.x * 256 + threadIdx.x;
  if (g < 32768) {
    const int e0 = g * 8;
    const int chunk = e0 >> 10;
    const int colL = (e0 >> 3) & 127;
    const int kg = chunk & 3, tks = chunk >> 2;
    const int ks = tks & 7, t = tks >> 3;
    const int col = t * 128 + colL;
    const int kb = ks * 32 + kg * 8;
    short8 v;
    #pragma unroll
    for (int e = 0; e < 8; ++e) v[e] = (short)f2bf(w1[col * 256 + kb + e]);
    *(short8*)(w1p + e0) = v;
  } else {
    const int e0 = (g - 32768) * 8;
    const int chunk = e0 >> 11;
    const int outcol = (e0 >> 3) & 255;
    const int kg = chunk & 3, tks = chunk >> 2;
    const int ks = tks & 3, t = tks >> 2;
    const int kb = t * 128 + ks * 32 + kg * 8;
    short8 v;
    #pragma unroll
    for (int e = 0; e < 8; ++e) v[e] = (short)f2bf(w2[outcol * 1024 + kb + e]);
    *(short8*)(w2p + e0) = v;
  }
}

// ---------------- bias+mask+pad table, lane-order: [cls][h][q=(i,r,j)][lane] ----------------
// value at [q][l]: n = 16*(q>>4) + (l>>4)*4 + ((q>>2)&3), m = 16*(q&3) + (l&15)
__global__ __launch_bounds__(256) void btab_build(const float* __restrict__ rpb, float* __restrict__ btab) {
  const int cls = blockIdx.x >> 3, h = blockIdx.x & 7;
  float* dst = btab + (size_t)(cls * 8 + h) * 4096;
  for (int e = threadIdx.x; e < 4096; e += 256) {
    const int q = e >> 6, l = e & 63;
    const int j = q & 3, r = (q >> 2) & 3, i = q >> 4;
    const int kg = l >> 4, rq = l & 15;
    const int n = 16 * i + kg * 4 + r;
    const int m = 16 * j + rq;
    float v;
    if (m >= 49) {
      v = -1e30f;
    } else if (n >= 49) {
      v = 0.f;
    } else {
      const int r1 = n / 7, c1 = n - r1 * 7;
      const int r2 = m / 7, c2 = m - r2 * 7;
      const int rel = (r1 - r2 + 6) * 13 + (c1 - c2 + 6);
      v = rpb[rel * 8 + h];
      const int reg1 = ((cls & 1) ? (r1 < 4 ? 1 : 2) : 0) * 3 + ((cls & 2) ? (c1 < 4 ? 1 : 2) : 0);
      const int reg2 = ((cls & 1) ? (r2 < 4 ? 1 : 2) : 0) * 3 + ((cls & 2) ? (c2 < 4 ? 1 : 2) : 0);
      if (reg1 != reg2) v -= 100.f;
    }
    dst[e] = v;
  }
}

// ---------------- LN1 + shift + window gather -> XY bf16 [CHUNK_ROWS][512] ----------------
__global__ __launch_bounds__(256) void ln_gather(
    const float* __restrict__ x, const float* __restrict__ y,
    const float* __restrict__ g1, const float* __restrict__ b1,
    u16* __restrict__ XY, int rowbase)
{
  const int wv = threadIdx.x >> 6, lane = threadIdx.x & 63;
  const int rl = blockIdx.x * 4 + wv;
  const int row = rowbase + rl;
  const int w = row / 49, n = row - w * 49;
  const int b = w >> 6, win = w & 63, wh = win >> 3, ww = win & 7;
  const int r = n / 7, c = n - r * 7;
  int oh = wh * 7 + r + 3; if (oh >= 56) oh -= 56;
  int ow = ww * 7 + c + 3; if (ow >= 56) ow -= 56;
  const size_t po = ((size_t)b * 3136 + oh * 56 + ow) * 256;
  const float4 g1v = ((const float4*)g1)[lane];
  const float4 b1v = ((const float4*)b1)[lane];
  u16* orow = XY + (size_t)rl * 512;
  #pragma unroll
  for (int mod = 0; mod < 2; ++mod) {
    const float* src = (mod ? y : x) + po;
    const float4 v = ((const float4*)src)[lane];
    float s = v.x + v.y + v.z + v.w;
    #pragma unroll
    for (int off = 1; off < 64; off <<= 1) s += __shfl_xor(s, off);
    const float mean = s * (1.0f / 256.0f);
    const float d0 = v.x - mean, d1 = v.y - mean, d2 = v.z - mean, d3 = v.w - mean;
    float sq = d0 * d0 + d1 * d1 + d2 * d2 + d3 * d3;
    #pragma unroll
    for (int off = 1; off < 64; off <<= 1) sq += __shfl_xor(sq, off);
    const float rstd = rsqrtf(sq * (1.0f / 256.0f) + 1e-5f);
    ushort4 o;
    o.x = f2bf(d0 * rstd * g1v.x + b1v.x);
    o.y = f2bf(d1 * rstd * g1v.y + b1v.y);
    o.z = f2bf(d2 * rstd * g1v.z + b1v.z);
    o.w = f2bf(d3 * rstd * g1v.w + b1v.w);
    *(ushort4*)(orow + mod * 256 + lane * 4) = o;
  }
}

// ---------------- QKV GEMM (128x128, XCD-swizzled); fragment-order output ----------------
__global__ __launch_bounds__(256) void qkv_gemm(
    const u16* __restrict__ A, const u16* __restrict__ Bw,
    const float* __restrict__ bias, u16* __restrict__ Qo)
{
  __shared__ __align__(16) u16 smem[128 * 128];
  u16* sA = smem;
  u16* sB = smem + 128 * 64;
  const int nx = gridDim.x;
  const int nwg = nx * gridDim.y;
  const int orig = blockIdx.y * nx + blockIdx.x;
  const int sw = (orig & 7) * (nwg >> 3) + (orig >> 3);
  const int m0  = (sw / nx) * 128;
  const int nn0 = (sw % nx) * 128;
  const int tid = threadIdx.x;
  const int lane = tid & 63;
  const int wv = tid >> 6;
  const int wm = wv >> 1, wn = wv & 1;
  const int rq = lane & 15, kg = lane >> 4;
  f32x4 acc[4][4];
  #pragma unroll
  for (int i = 0; i < 4; ++i)
    #pragma unroll
    for (int j = 0; j < 4; ++j) acc[i][j] = f32x4{0,0,0,0};

  for (int kt = 0; kt < 8; ++kt) {
    if (kt) __syncthreads();
    #pragma unroll
    for (int i = 0; i < 4; ++i) {
      const int c = i * 256 + tid;
      gload16(A + (size_t)(m0 + (c >> 3)) * 512 + kt * 64 + (c & 7) * 8, sA + c * 8);
    }
    #pragma unroll
    for (int i = 0; i < 4; ++i) {
      const int c = i * 256 + tid;
      gload16(Bw + (size_t)(nn0 + (c >> 3)) * 512 + kt * 64 + (c & 7) * 8, sB + c * 8);
    }
    __syncthreads();
    #pragma unroll
    for (int k0 = 0; k0 < 2; ++k0) {
      short8 af[4], bf8[4];
      #pragma unroll
      for (int mt = 0; mt < 4; ++mt)
        af[mt] = *(const short8*)(sA + (wm * 64 + mt * 16 + rq) * 64 + k0 * 32 + kg * 8);
      #pragma unroll
      for (int nt = 0; nt < 4; ++nt)
        bf8[nt] = *(const short8*)(sB + (wn * 64 + nt * 16 + rq) * 64 + k0 * 32 + kg * 8);
      #pragma unroll
      for (int mt = 0; mt < 4; ++mt)
        #pragma unroll
        for (int nt = 0; nt < 4; ++nt)
          acc[mt][nt] = mfma16(af[mt], bf8[nt], acc[mt][nt]);
    }
  }
  // ---- C tile -> LDS (swizzled) ----
  __syncthreads();
  const int t = nn0 >> 9;
  const int hbase = (nn0 & 511) >> 6;
  const float sc = (t == 0) ? 0.17677669529663687f : 1.0f;
  #pragma unroll
  for (int nt = 0; nt < 4; ++nt) {
    const int col = wn * 64 + nt * 16 + rq;
    const float bc = bias[nn0 + col];
    const int c = col >> 3;
    #pragma unroll
    for (int mt = 0; mt < 4; ++mt)
      #pragma unroll
      for (int r = 0; r < 4; ++r) {
        const int row = wm * 64 + mt * 16 + kg * 4 + r;
        smem[row * 128 + (((c & 8) | ((c ^ row) & 7)) << 3) + (col & 7)] =
            f2bf((acc[mt][nt][r] + bc) * sc);
      }
  }
  __syncthreads();
  // ---- dest-linear coalesced stores into fragment-order planes ----
  #pragma unroll
  for (int it = 0; it < 8; ++it) {
    const int idx = it * 256 + tid;            // [hh:1][c8:3][rowL:7]
    const int hh = idx >> 10;
    const int c8 = (idx >> 7) & 7;
    const int rowL = idx & 127;
    const int c = hh * 8 + c8;
    const int grow = m0 + rowL;
    const u32 w49 = (u32)grow / 49u;
    const u32 tok = (u32)grow - w49 * 49u;
    const short8 v = *(const short8*)(smem + rowL * 128 + (((c & 8) | ((c ^ rowL) & 7)) << 3));
    *(short8*)(Qo + (size_t)(t * 8 + hbase + hh) * PLANE + (size_t)w49 * 3136 + (c8 * 49 + tok) * 8) = v;
  }
}

// ---------------- barrier-free attention (2-wave blocks); fragment-order q/k/v + lane-order table ----------------
__global__ __launch_bounds__(128, 3) void attn3(
    const u16* __restrict__ qkv, const float* __restrict__ btab,
    u16* __restrict__ concat, int wbase)
{
  __shared__ __align__(16) u16 sP[2][3136];
  __shared__ __align__(16) u16 sVT[2][4608];

  const int tid = threadIdx.x;
  const int wv = tid >> 6, lane = tid & 63;
  const int rq = lane & 15, kg = lane >> 4;
  const int gw = blockIdx.x * 2 + wv;
  const int wl = gw >> 3, h = gw & 7;
  const int w = wbase + wl;
  const int win = w & 63, wh = win >> 3, ww = win & 7;
  const int cls = ((wh == 7) ? 1 : 0) | ((ww == 7) ? 2 : 0);
  const float* Tb = btab + (size_t)(cls * 8 + h) * 4096;
  u16* sPw = sP[wv];
  u16* sVw = sVT[wv];

  const u16* qbase = qkv + (size_t)h * PLANE + (size_t)wl * 3136;
  const u16* kbase = qkv + KOFF + (size_t)h * PLANE + (size_t)wl * 3136;
  const u16* vbase = qkv + VOFF + (size_t)h * PLANE + (size_t)wl * 3136;

  // ---- v fragment loads (lane-linear), issued early ----
  short8 vreg[4][2];
  #pragma unroll
  for (int t = 0; t < 4; ++t) {
    const int tokc = (16 * t + rq) > 48 ? 48 : (16 * t + rq);
    #pragma unroll
    for (int h2 = 0; h2 < 2; ++h2)
      vreg[t][h2] = *(const short8*)(vbase + ((h2 * 4 + kg) * 49 + tokc) * 8);
  }

  // ---- K fragments, then S with per-i Q loads (all lane-linear) ----
  short8 ak[4][2];
  #pragma unroll
  for (int j = 0; j < 4; ++j) {
    const int rr = (16 * j + rq) > 48 ? 48 : (16 * j + rq);
    ak[j][0] = *(const short8*)(kbase + (kg * 49 + rr) * 8);
    ak[j][1] = *(const short8*)(kbase + ((4 + kg) * 49 + rr) * 8);
  }
  f32x4 sacc[4][4];
  #pragma unroll
  for (int i = 0; i < 4; ++i)
    #pragma unroll
    for (int j = 0; j < 4; ++j) sacc[i][j] = f32x4{0,0,0,0};
  #pragma unroll
  for (int i = 0; i < 4; ++i) {
    const int rr = (16 * i + rq) > 48 ? 48 : (16 * i + rq);
    const short8 a0 = *(const short8*)(qbase + (kg * 49 + rr) * 8);
    const short8 a1 = *(const short8*)(qbase + ((4 + kg) * 49 + rr) * 8);
    #pragma unroll
    for (int j = 0; j < 4; ++j) {
      sacc[i][j] = mfma16(a0, ak[j][0], sacc[i][j]);
      sacc[i][j] = mfma16(a1, ak[j][1], sacc[i][j]);
    }
  }

  // ---- write v into LDS vT (conflict-free: row ^ (kg<<4)) ----
  #pragma unroll
  for (int t = 0; t < 4; ++t) {
    const int row = 16 * t + rq;
    #pragma unroll
    for (int h2 = 0; h2 < 2; ++h2) {
      const int c0 = kg * 8 + h2 * 32;
      #pragma unroll
      for (int j = 0; j < 8; ++j)
        sVw[(c0 + j) * 72 + (row ^ (kg << 4))] = (u16)vreg[t][h2][j];
    }
  }

  // ---- table-driven softmax (coalesced table reads); P -> sPw ----
  #pragma unroll
  for (int i = 0; i < 4; ++i) {
    #pragma unroll
    for (int r = 0; r < 4; ++r) {
      const int n = 16 * i + kg * 4 + r;
      const float* Tq = Tb + ((i * 4 + r) * 4) * 64 + lane;
      float pv[4];
      #pragma unroll
      for (int j = 0; j < 4; ++j)
        pv[j] = sacc[i][j][r] + Tq[j * 64];
      float mx = fmaxf(fmaxf(pv[0], pv[1]), fmaxf(pv[2], pv[3]));
      #pragma unroll
      for (int off = 1; off < 16; off <<= 1) mx = fmaxf(mx, __shfl_xor(mx, off));
      float sm = 0.f;
      #pragma unroll
      for (int j = 0; j < 4; ++j) { const float e = __expf(pv[j] - mx); pv[j] = e; sm += e; }
      #pragma unroll
      for (int off = 1; off < 16; off <<= 1) sm += __shfl_xor(sm, off);
      const float inv = 1.0f / sm;
      if (n < 49) {
        #pragma unroll
        for (int j = 0; j < 4; ++j) {
          const int col = 16 * j + rq;
          sPw[n * 64 + (((col >> 3) ^ (n & 7)) << 3) + (col & 7)] = f2bf(pv[j] * inv);
        }
      }
    }
  }

  // ---- PV: A = P (LDS), B = vT (LDS b128, pad toks masked) ----
  f32x4 oacc[4][4];
  #pragma unroll
  for (int i = 0; i < 4; ++i)
    #pragma unroll
    for (int j = 0; j < 4; ++j) oacc[i][j] = f32x4{0,0,0,0};
  #pragma unroll
  for (int m0v = 0; m0v < 2; ++m0v) {
    short8 av[4];
    #pragma unroll
    for (int ct = 0; ct < 4; ++ct) {
      const int col = ct * 16 + rq;
      const int s = (col >> 3) & 3;
      short8 vvv = *(const short8*)(sVw + col * 72 + ((m0v * 32 + kg * 8) ^ (s << 4)));
      if (m0v == 1) {
        if (kg == 3) {
          #pragma unroll
          for (int e = 0; e < 8; ++e) vvv[e] = 0;
        } else if (kg == 2) {
          #pragma unroll
          for (int e = 1; e < 8; ++e) vvv[e] = 0;
        }
      }
      av[ct] = vvv;
    }
    #pragma unroll
    for (int i = 0; i < 4; ++i) {
      const int rr = (16 * i + rq) > 48 ? 48 : (16 * i + rq);
      const int ch = (m0v * 4 + kg) ^ (rr & 7);
      const short8 pa = *(const short8*)(sPw + rr * 64 + ch * 8);
      #pragma unroll
      for (int ct = 0; ct < 4; ++ct)
        oacc[i][ct] = mfma16(pa, av[ct], oacc[i][ct]);
    }
  }

  // ---- repack out_h through LDS (reuse sPw), coalesced b128 store ----
  __builtin_amdgcn_s_waitcnt(0);
  #pragma unroll
  for (int i = 0; i < 4; ++i)
    #pragma unroll
    for (int ct = 0; ct < 4; ++ct)
      #pragma unroll
      for (int r = 0; r < 4; ++r) {
        const int n = 16 * i + kg * 4 + r;
        if (n < 49) {
          const int col = ct * 16 + rq;
          sPw[n * 64 + (((col >> 3) ^ (n & 7)) << 3) + (col & 7)] = f2bf(oacc[i][ct][r]);
        }
      }
  u16* crow = concat + (size_t)(wl * 49) * 512 + h * 64;
  #pragma unroll
  for (int it = 0; it < 7; ++it) {
    const int c = it * 64 + lane;
    if (c < 392) {
      const int m = c >> 3, s = c & 7;
      const short8 vvv = *(const short8*)(sPw + m * 64 + ((s ^ (m & 7)) << 3));
      *(short8*)(crow + (size_t)m * 512 + s * 8) = vvv;
    }
  }
}

// ---------------- proj GEMM + LN2 fused: BM=64, BN=256 (full row); grid 392 ----------------
__global__ __launch_bounds__(256, 3) void projln(
    const u16* __restrict__ A, const u16* __restrict__ Bw,
    const float* __restrict__ bias, const float* __restrict__ x,
    const float* __restrict__ g2, const float* __restrict__ b2,
    float* __restrict__ out, u16* __restrict__ xn2, int rowbase)
{
  __shared__ __align__(16) u16 sA[64 * 64];
  __shared__ __align__(16) u16 sB[256 * 64];
  const int m0 = blockIdx.x * 64;
  const int tid = threadIdx.x;
  const int lane = tid & 63;
  const int wv = tid >> 6;
  const int rq = lane & 15, kg = lane >> 4;
  f32x4 acc[16];
  #pragma unroll
  for (int j = 0; j < 16; ++j) acc[j] = f32x4{0,0,0,0};

  for (int kt = 0; kt < 8; ++kt) {
    if (kt) __syncthreads();
    #pragma unroll
    for (int i = 0; i < 2; ++i) {
      const int c = i * 256 + tid;
      gload16(A + (size_t)(m0 + (c >> 3)) * 512 + kt * 64 + (c & 7) * 8, sA + c * 8);
    }
    #pragma unroll
    for (int i = 0; i < 8; ++i) {
      const int c = i * 256 + tid;
      gload16(Bw + (size_t)(c >> 3) * 512 + kt * 64 + (c & 7) * 8, sB + c * 8);
    }
    __syncthreads();
    #pragma unroll
    for (int k0 = 0; k0 < 2; ++k0) {
      const short8 af = *(const short8*)(sA + (wv * 16 + rq) * 64 + k0 * 32 + kg * 8);
      #pragma unroll
      for (int nt = 0; nt < 16; ++nt) {
        const short8 bf8 = *(const short8*)(sB + (nt * 16 + rq) * 64 + k0 * 32 + kg * 8);
        acc[nt] = mfma16(af, bf8, acc[nt]);
      }
    }
  }

  float br[16], g2r[16], b2r[16];
  #pragma unroll
  for (int nt = 0; nt < 16; ++nt) {
    const int col = nt * 16 + rq;
    br[nt] = bias[col]; g2r[nt] = g2[col]; b2r[nt] = b2[col];
  }
  #pragma unroll
  for (int r = 0; r < 4; ++r) {
    const int row = m0 + wv * 16 + kg * 4 + r;
    const u32 g = (u32)(rowbase + row);
    const u32 w = g / 49u; const u32 n = g - w * 49u;
    const int b = w >> 6, win = w & 63, wh = win >> 3, ww = win & 7;
    const u32 rr = n / 7u; const u32 cc = n - rr * 7u;
    int oh = wh * 7 + (int)rr + 3; if (oh >= 56) oh -= 56;
    int ow = ww * 7 + (int)cc + 3; if (ow >= 56) ow -= 56;
    const size_t po = ((size_t)b * 3136 + oh * 56 + ow) * 256;
    float vals[16];
    float s = 0.f;
    #pragma unroll
    for (int nt = 0; nt < 16; ++nt) {
      const float v = acc[nt][r] + br[nt] + x[po + nt * 16 + rq];
      vals[nt] = v; s += v;
    }
    #pragma unroll
    for (int off = 1; off < 16; off <<= 1) s += __shfl_xor(s, off);
    const float mean = s * (1.0f / 256.0f);
    float sq = 0.f;
    #pragma unroll
    for (int nt = 0; nt < 16; ++nt) { const float d_ = vals[nt] - mean; sq += d_ * d_; }
    #pragma unroll
    for (int off = 1; off < 16; off <<= 1) sq += __shfl_xor(sq, off);
    const float rstd = rsqrtf(sq * (1.0f / 256.0f) + 1e-5f);
    #pragma unroll
    for (int nt = 0; nt < 16; ++nt) {
      const int col = nt * 16 + rq;
      out[po + col] = vals[nt];
      xn2[po + col] = f2bf((vals[nt] - mean) * rstd * g2r[nt] + b2r[nt]);
    }
  }
}

// ---------------- fused MLP (R8-v1 structure + fragment-order weights + cheap GELU) ----------------
__global__ __launch_bounds__(256, 3) void fused_mlp(
    const u16* __restrict__ xn2, const u16* __restrict__ w1p,
    const float* __restrict__ bf1, const u16* __restrict__ w2p,
    const float* __restrict__ bf2v, float* __restrict__ out)
{
  __shared__ __align__(16) u16 sX[64 * 256];   // xn2 panel, chunk-swizzled
  __shared__ __align__(16) u16 sH[64 * 128];   // h tile, chunk-swizzled

  const int m0 = blockIdx.x * 64;
  const int tid = threadIdx.x;
  const int wv = tid >> 6, lane = tid & 63;
  const int rq = lane & 15, kg = lane >> 4;

  #pragma unroll
  for (int i = 0; i < 8; ++i) {
    const int c = i * 256 + tid;
    const int row = c >> 5, ch = c & 31;
    const int sch = (ch & 24) | ((ch ^ row) & 7);
    gload16(xn2 + (size_t)(m0 + row) * 256 + sch * 8, sX + c * 8);
  }

  f32x4 acc2[4][4];
  #pragma unroll
  for (int i = 0; i < 4; ++i)
    #pragma unroll
    for (int j = 0; j < 4; ++j) acc2[i][j] = f32x4{0,0,0,0};

  __syncthreads();

  for (int t = 0; t < 8; ++t) {
    f32x4 a1[4][2];
    #pragma unroll
    for (int i = 0; i < 4; ++i)
      #pragma unroll
      for (int j = 0; j < 2; ++j) a1[i][j] = f32x4{0,0,0,0};
    #pragma unroll
    for (int ks = 0; ks < 8; ++ks) {
      const u16* wb = w1p + ((size_t)((t * 8 + ks) * 4 + kg)) * 1024;
      short8 bfr[2];
      #pragma unroll
      for (int nt = 0; nt < 2; ++nt)
        bfr[nt] = *(const short8*)(wb + (wv * 32 + nt * 16 + rq) * 8);
      #pragma unroll
      for (int mt = 0; mt < 4; ++mt) {
        const int R = mt * 16 + rq;
        const int wk = ks * 4 + kg;
        const short8 af = *(const short8*)(sX + R * 256 + ((wk & 24) | ((wk ^ R) & 7)) * 8);
        #pragma unroll
        for (int nt = 0; nt < 2; ++nt)
          a1[mt][nt] = mfma16(af, bfr[nt], a1[mt][nt]);
      }
    }
    __syncthreads();
    #pragma unroll
    for (int nt = 0; nt < 2; ++nt) {
      const int col = wv * 32 + nt * 16 + rq;
      const float bb = bf1[t * 128 + col];
      const int ch = col >> 3;
      #pragma unroll
      for (int mt = 0; mt < 4; ++mt)
        #pragma unroll
        for (int r = 0; r < 4; ++r) {
          const int row = mt * 16 + kg * 4 + r;
          sH[row * 128 + ((ch & 8) | ((ch ^ row) & 7)) * 8 + (col & 7)] =
              f2bf(gelu_s(a1[mt][nt][r] + bb));
        }
    }
    __syncthreads();
    #pragma unroll
    for (int ks = 0; ks < 4; ++ks) {
      const u16* wb = w2p + ((size_t)((t * 4 + ks) * 4 + kg)) * 2048;
      short8 bfr2[4];
      #pragma unroll
      for (int nt = 0; nt < 4; ++nt)
        bfr2[nt] = *(const short8*)(wb + (wv * 64 + nt * 16 + rq) * 8);
      #pragma unroll
      for (int mt = 0; mt < 4; ++mt) {
        const int R = mt * 16 + rq;
        const int wk = ks * 4 + kg;
        const short8 af = *(const short8*)(sH + R * 128 + ((wk & 8) | ((wk ^ R) & 7)) * 8);
        #pragma unroll
        for (int nt = 0; nt < 4; ++nt)
          acc2[mt][nt] = mfma16(af, bfr2[nt], acc2[mt][nt]);
      }
    }
  }

  #pragma unroll
  for (int nt = 0; nt < 4; ++nt) {
    const int col = wv * 64 + nt * 16 + rq;
    const float bb = bf2v[col];
    #pragma unroll
    for (int mt = 0; mt < 4; ++mt)
      #pragma unroll
      for (int r = 0; r < 4; ++r) {
        float* p = out + (size_t)(m0 + mt * 16 + kg * 4 + r) * 256 + col;
        *p = acc2[mt][nt][r] + bb + *p;
      }
  }
}

extern "C" void kernel_launch(void* const* d_in, const int* in_sizes, int n_in,
                              void* d_out, int out_size, void* d_ws, size_t ws_size,
                              hipStream_t stream) {
  const float* x      = (const float*)d_in[0];
  const float* y      = (const float*)d_in[1];
  const float* g1     = (const float*)d_in[2];
  const float* b1     = (const float*)d_in[3];
  const float* rpb    = (const float*)d_in[4];
  const float* w_qkv  = (const float*)d_in[5];
  const float* b_qkv  = (const float*)d_in[6];
  const float* w_proj = (const float*)d_in[7];
  const float* b_proj = (const float*)d_in[8];
  const float* g2     = (const float*)d_in[9];
  const float* b2     = (const float*)d_in[10];
  const float* w_fc1  = (const float*)d_in[11];
  const float* b_fc1  = (const float*)d_in[12];
  const float* w_fc2  = (const float*)d_in[13];
  const float* b_fc2  = (const float*)d_in[14];
  float* out = (float*)d_out;

  u16* wsp = (u16*)d_ws;
  u16* wqkv_bf  = wsp;                       //  786432
  u16* wproj_bf = wsp + 786432;              //  131072
  u16* w1p      = wsp + 917504;              //  262144 (fragment-order)
  u16* w2p      = wsp + 1179648;             //  262144 (fragment-order)
  float* btab   = (float*)(wsp + 1441792);   //  131072 f32 (lane-order)
  u16* xn2      = wsp + 1703936;             //  25690112
  u16* XYc      = wsp + 27394048;            //  12845056 (25088 x 512)
  u16* qkvc     = wsp + 40239104;            //  24 planes x 25088 x 64 (fragment-order)

  convall<<<896, 256, 0, stream>>>(w_qkv, w_proj, wqkv_bf, wproj_bf);
  repack_mlp<<<256, 256, 0, stream>>>(w_fc1, w_fc2, w1p, w2p);
  btab_build<<<32, 256, 0, stream>>>(rpb, btab);

  for (int c = 0; c < 4; ++c) {
    ln_gather<<<6272, 256, 0, stream>>>(x, y, g1, b1, XYc, c * CHUNK_ROWS);
    qkv_gemm<<<dim3(12, 196), 256, 0, stream>>>(XYc, wqkv_bf, b_qkv, qkvc);
    attn3<<<2048, 128, 0, stream>>>(qkvc, btab, XYc, c * 512);
    projln<<<392, 256, 0, stream>>>(XYc, wproj_bf, b_proj, x, g2, b2, out, xn2, c * CHUNK_ROWS);
  }

  fused_mlp<<<1568, 256, 0, stream>>>(xn2, w1p, b_fc1, w2p, b_fc2, out);
}